// Round 11
// baseline (119.183 us; speedup 1.0000x reference)
//
#include <hip/hip_runtime.h>
#include <hip/hip_fp16.h>

#define N_NODES 100000
#define N_EDGES 3200000
#define NBKT 782            // buckets of 128 nodes (dst >> 7)
#define HB 256              // hist blocks
#define HEPB (N_EDGES / HB) // 12500 edges per hist block
#define EB2 512             // scatter blocks
#define EPB2 (N_EDGES / EB2) // 6250 edges per scatter block
#define SORT_CAP 5120       // per-bucket sorted-edge LDS capacity (20 KB)

// ---------------------------------------------------------------------------
// h2[i][c] = fp16( sum_k x[i][k] * W1[c][k] )  -- h stored as __half2[N][8]
// ---------------------------------------------------------------------------
__global__ void linear1_kernel(const float* __restrict__ x,
                               const float* __restrict__ W1,
                               __half2* __restrict__ h2, int n) {
    __shared__ float w[16 * 58];
    for (int idx = threadIdx.x; idx < 16 * 58; idx += blockDim.x)
        w[idx] = W1[idx];
    __syncthreads();

    int i = blockIdx.x * blockDim.x + threadIdx.x;
    if (i >= n) return;

    float xv[58];
    const float* xr = x + (long)i * 58;
#pragma unroll
    for (int k = 0; k < 58; ++k) xv[k] = xr[k];

    __half2 o[8];
#pragma unroll
    for (int q = 0; q < 8; ++q) {
        float a[2];
#pragma unroll
        for (int r = 0; r < 2; ++r) {
            int c = q * 2 + r;
            float acc = 0.0f;
#pragma unroll
            for (int k = 0; k < 58; ++k) acc += xv[k] * w[c * 58 + k];
            a[r] = acc;
        }
        o[q] = __floats2half2_rn(a[0], a[1]);
    }
    float4* dst = (float4*)(h2 + (long)i * 8);
    float4* src = (float4*)o;
    dst[0] = src[0];
    dst[1] = src[1];
}

// ---------------------------------------------------------------------------
// Per-bucket totals only (global int atomics). Self-detects int64 vs int32
// (odd 32-bit words all zero => int64) — no separate detect kernel.
// ---------------------------------------------------------------------------
__global__ void hist_kernel(const int* __restrict__ ei32,
                            const long long* __restrict__ ei64,
                            int* __restrict__ btot) {
    __shared__ int hist[NBKT];
    __shared__ int dflag;
    int tid = threadIdx.x;
    if (tid == 0) dflag = 0;
    for (int i = tid; i < NBKT; i += 512) hist[i] = 0;
    __syncthreads();
    if (tid < 512 && ((const unsigned int*)ei32)[2 * tid + 1] != 0u)
        atomicOr(&dflag, 1);
    __syncthreads();
    bool i64 = (dflag == 0);

    long base = (long)blockIdx.x * HEPB;
    for (int k = tid; k < HEPB; k += 512) {
        long e = base + k;
        int dst = i64 ? (int)ei64[N_EDGES + e] : ei32[N_EDGES + e];
        atomicAdd(&hist[dst >> 7], 1);
    }
    __syncthreads();
    for (int b = tid; b < NBKT; b += 512)
        if (hist[b] > 0) atomicAdd(&btot[b], hist[b]);
}

// ---------------------------------------------------------------------------
// One-block exclusive scan over the 782 bucket totals -> bstart + bcursor.
// ---------------------------------------------------------------------------
__global__ void bucket_scan_kernel(const int* __restrict__ btot,
                                   int* __restrict__ bstart,
                                   int* __restrict__ bcursor) {
    __shared__ int tmp[1024];
    int i = threadIdx.x;
    int v = (i < NBKT) ? btot[i] : 0;
    tmp[i] = v;
    __syncthreads();
#pragma unroll
    for (int d = 1; d < 1024; d <<= 1) {
        int t = (i >= d) ? tmp[i - d] : 0;
        __syncthreads();
        tmp[i] += t;
        __syncthreads();
    }
    if (i < NBKT) { int s = tmp[i] - v; bstart[i] = s; bcursor[i] = s; }
    if (i == 0) bstart[NBKT] = N_EDGES;
}

// ---------------------------------------------------------------------------
// Scatter: per-block LDS counting sort by bucket, per-bucket global region
// CLAIMED via atomicAdd(bcursor) (bucket-contiguous; intra-bucket block
// order nondeterministic => only reorders fp sums, ~1e-5 noise), then dense
// stream-out. 38.5 KB LDS -> 2 blocks/CU, grid 512 fully resident.
// ---------------------------------------------------------------------------
__global__ void __launch_bounds__(1024, 2)
scatter_sort_kernel(const int* __restrict__ ei32,
                    const long long* __restrict__ ei64,
                    int* __restrict__ bcursor,
                    unsigned int* __restrict__ packed) {
    __shared__ unsigned int vals[EPB2];     // 25 KB bucket-grouped payloads
    __shared__ int hist[NBKT];              // counts, then reused as cursors
    __shared__ int lstart[NBKT + 1];
    __shared__ int gbase[NBKT];
    __shared__ int tmp[1024];
    __shared__ int dflag;

    int tid = threadIdx.x;
    if (tid == 0) dflag = 0;
    for (int i = tid; i < NBKT; i += 1024) hist[i] = 0;
    __syncthreads();
    if (tid < 512 && ((const unsigned int*)ei32)[2 * tid + 1] != 0u)
        atomicOr(&dflag, 1);
    __syncthreads();
    bool i64 = (dflag == 0);
    long base = (long)blockIdx.x * EPB2;

    // pass 1: dst-only local histogram
    for (int k = tid; k < EPB2; k += 1024) {
        long e = base + k;
        int dst = i64 ? (int)ei64[N_EDGES + e] : ei32[N_EDGES + e];
        atomicAdd(&hist[dst >> 7], 1);
    }
    __syncthreads();

    // pass 2: local exclusive scan (1024-wide, entries >= NBKT padded 0)
    int v = (tid < NBKT) ? hist[tid] : 0;
    tmp[tid] = v;
    __syncthreads();
#pragma unroll
    for (int d = 1; d < 1024; d <<= 1) {
        int t = (tid >= d) ? tmp[tid - d] : 0;
        __syncthreads();
        tmp[tid] += t;
        __syncthreads();
    }
    if (tid < NBKT) lstart[tid] = tmp[tid] - v;
    if (tid == 0) lstart[NBKT] = EPB2;
    __syncthreads();

    // pass 3: claim this block's slice of each bucket's global region
    for (int b = tid; b < NBKT; b += 1024) {
        int c = hist[b];
        int gb = (c > 0) ? atomicAdd(&bcursor[b], c) : 0;
        gbase[b] = gb - lstart[b];
    }
    __syncthreads();
    if (tid < NBKT) hist[tid] = lstart[tid];   // reuse hist as scatter cursor
    __syncthreads();

    // pass 4: re-read edges; cursor-scatter payload into bucket-grouped LDS
    for (int k = tid; k < EPB2; k += 1024) {
        long e = base + k;
        int src, dst;
        if (i64) { src = (int)ei64[e]; dst = (int)ei64[N_EDGES + e]; }
        else     { src = ei32[e];      dst = ei32[N_EDGES + e]; }
        int b = dst >> 7;
        int p = atomicAdd(&hist[b], 1);
        vals[p] = ((unsigned int)(dst & 127) << 17) | (unsigned int)src;
    }
    __threadfence_block();
    __syncthreads();

    // pass 5: dense stream-out; bucket of slot j = largest b, lstart[b] <= j
    for (int j = tid; j < EPB2; j += 1024) {
        int lo = 0, hi = NBKT;
        while (lo < hi) {
            int mid = (lo + hi + 1) >> 1;
            if (lstart[mid] <= j) lo = mid; else hi = mid - 1;
        }
        packed[gbase[lo] + j] = vals[j];
    }
}

// ---------------------------------------------------------------------------
// Phase B1: per-bucket counting sort in LDS, written BACK TO GLOBAL.
// ---------------------------------------------------------------------------
__global__ void __launch_bounds__(512, 4)
sort_kernel(unsigned int* __restrict__ packed,
            const int* __restrict__ bstart,
            int* __restrict__ ndeg,
            int* __restrict__ nstart,
            int* __restrict__ bsort) {
    __shared__ unsigned int sorted[SORT_CAP];  // 20 KB
    __shared__ int hist[128];
    __shared__ int starts[128];
    __shared__ int curs[128];
    __shared__ int tmp[512];

    int b = blockIdx.x;
    int tid = threadIdx.x;
    int start = bstart[b];
    int end = bstart[b + 1];
    int m = end - start;

    if (tid < 128) hist[tid] = 0;
    __syncthreads();

    // 1. per-node histogram
    for (int k = tid; k < m; k += 512)
        atomicAdd(&hist[(int)(packed[start + k] >> 17)], 1);
    __syncthreads();

    // 2. exclusive scan
    int v = (tid < 128) ? hist[tid] : 0;
    tmp[tid] = v;
    __syncthreads();
#pragma unroll
    for (int d = 1; d < 512; d <<= 1) {
        int t = (tid >= d) ? tmp[tid - d] : 0;
        __syncthreads();
        tmp[tid] += t;
        __syncthreads();
    }
    if (tid < 128) {
        int s = tmp[tid] - v;
        starts[tid] = s;
        curs[tid] = s;
    }
    __syncthreads();

    bool fast = (m <= SORT_CAP);   // uniform across the block
    if (fast) {
        // 3. cursor-scatter src into sorted[]
        for (int k = tid; k < m; k += 512) {
            unsigned int w = packed[start + k];
            int l = (int)(w >> 17);
            int p = atomicAdd(&curs[l], 1);
            sorted[p] = w & 0x1FFFFu;
        }
        __threadfence_block();
        __syncthreads();
        // 4. write node-sorted src list back to global (dense, coalesced)
        for (int k = tid; k < m; k += 512)
            packed[start + k] = sorted[k];
    }

    // 5. per-node meta
    if (tid < 128) {
        int g = b * 128 + tid;
        if (g < N_NODES) {
            ndeg[g] = hist[tid];
            nstart[g] = start + starts[tid];
        }
    }
    if (tid == 0) bsort[b] = fast ? 1 : 0;
}

// ---------------------------------------------------------------------------
// Phase B2: barrier-free, LDS-free gather. 8 lanes per node, each lane owns
// 2 channels; unroll-4; fused mean + bias + relu + W2-dot + b2; shfl-reduce.
// ---------------------------------------------------------------------------
__global__ void __launch_bounds__(512, 8)
gather_kernel(const unsigned int* __restrict__ packed,
              const int* __restrict__ ndeg,
              const int* __restrict__ nstart,
              const int* __restrict__ bsort,
              const int* __restrict__ bstart,
              const __half2* __restrict__ h2,
              const float* __restrict__ b1,
              const float* __restrict__ W2,
              const float* __restrict__ b2,
              float* __restrict__ out) {
    int bb = blockIdx.x;                         // 2*NBKT blocks
    int b = bb >> 1;
    int l = (bb & 1) * 64 + (threadIdx.x >> 3);  // node-in-bucket 0..127
    int c = threadIdx.x & 7;                     // channel pair 0..7
    int g = b * 128 + l;
    if (g >= N_NODES) return;                    // group-uniform; no barriers

    int deg = ndeg[g];
    float2 acc0 = {0.0f, 0.0f}, acc1 = {0.0f, 0.0f};

    if (bsort[b]) {
        int p = nstart[g], pend = p + deg;
        for (; p + 3 < pend; p += 4) {
            int sA = (int)packed[p];
            int sB = (int)packed[p + 1];
            int sC = (int)packed[p + 2];
            int sD = (int)packed[p + 3];
            float2 fA = __half22float2(h2[(long)sA * 8 + c]);
            float2 fB = __half22float2(h2[(long)sB * 8 + c]);
            float2 fC = __half22float2(h2[(long)sC * 8 + c]);
            float2 fD = __half22float2(h2[(long)sD * 8 + c]);
            acc0.x += fA.x + fC.x; acc0.y += fA.y + fC.y;
            acc1.x += fB.x + fD.x; acc1.y += fB.y + fD.y;
        }
        for (; p < pend; ++p) {
            float2 f = __half22float2(h2[(long)packed[p] * 8 + c]);
            acc0.x += f.x; acc0.y += f.y;
        }
    } else {
        // never-expected universal fallback: filter-scan the whole bucket
        int bs = bstart[b];
        int be = bstart[b + 1];
        for (int p = bs; p < be; ++p) {
            unsigned int w = packed[p];
            if ((int)(w >> 17) == l) {
                float2 f = __half22float2(h2[(long)(w & 0x1FFFFu) * 8 + c]);
                acc0.x += f.x; acc0.y += f.y;
            }
        }
    }

    float inv = 1.0f / fmaxf((float)deg, 1.0f);
    float sx = acc0.x + acc1.x, sy = acc0.y + acc1.y;
    float v = fmaxf(sx * inv + b1[2 * c], 0.0f)     * W2[2 * c]
            + fmaxf(sy * inv + b1[2 * c + 1], 0.0f) * W2[2 * c + 1];
    v += __shfl_xor(v, 1);
    v += __shfl_xor(v, 2);
    v += __shfl_xor(v, 4);
    if (c == 0) out[g] = v + b2[0];
}

// ---------------------------------------------------------------------------
// Fallback path (R0): atomic value scatter + finalize. Used if ws too small.
// ---------------------------------------------------------------------------
__global__ void detect_i64_kernel(const unsigned int* __restrict__ ei,
                                  unsigned int* __restrict__ flag) {
    unsigned int v = 0;
    int lane = threadIdx.x;  // 64 threads
    for (int j = lane; j < 512; j += 64) v |= ei[2 * j + 1];
    unsigned long long any_nonzero = __ballot(v != 0u);
    if (lane == 0) *flag = (any_nonzero == 0ULL) ? 1u : 0u;
}

__global__ void linear1_f32_kernel(const float* __restrict__ x,
                                   const float* __restrict__ W1,
                                   float* __restrict__ h, int n) {
    __shared__ float w[16 * 58];
    for (int idx = threadIdx.x; idx < 16 * 58; idx += blockDim.x)
        w[idx] = W1[idx];
    __syncthreads();
    int i = blockIdx.x * blockDim.x + threadIdx.x;
    if (i >= n) return;
    float xv[58];
    const float* xr = x + (long)i * 58;
#pragma unroll
    for (int k = 0; k < 58; ++k) xv[k] = xr[k];
#pragma unroll
    for (int cq = 0; cq < 4; ++cq) {
        float a[4];
#pragma unroll
        for (int r = 0; r < 4; ++r) {
            int ch = cq * 4 + r;
            float acc = 0.0f;
#pragma unroll
            for (int k = 0; k < 58; ++k) acc += xv[k] * w[ch * 58 + k];
            a[r] = acc;
        }
        ((float4*)(h + (long)i * 16))[cq] = make_float4(a[0], a[1], a[2], a[3]);
    }
}

__global__ void scatter_kernel(const int* __restrict__ ei32,
                               const long long* __restrict__ ei64,
                               const unsigned int* __restrict__ flag,
                               const float* __restrict__ h,
                               float* __restrict__ summed,
                               float* __restrict__ cnt) {
    long e = (long)blockIdx.x * blockDim.x + threadIdx.x;
    if (e >= N_EDGES) return;
    long src, dst;
    if (*flag) { src = (long)ei64[e]; dst = (long)ei64[N_EDGES + e]; }
    else       { src = (long)ei32[e]; dst = (long)ei32[N_EDGES + e]; }
    const float4* hs = (const float4*)(h + src * 16);
    float4 a = hs[0], b = hs[1], c = hs[2], d = hs[3];
    float* o = summed + dst * 16;
    atomicAdd(o + 0,  a.x); atomicAdd(o + 1,  a.y);
    atomicAdd(o + 2,  a.z); atomicAdd(o + 3,  a.w);
    atomicAdd(o + 4,  b.x); atomicAdd(o + 5,  b.y);
    atomicAdd(o + 6,  b.z); atomicAdd(o + 7,  b.w);
    atomicAdd(o + 8,  c.x); atomicAdd(o + 9,  c.y);
    atomicAdd(o + 10, c.z); atomicAdd(o + 11, c.w);
    atomicAdd(o + 12, d.x); atomicAdd(o + 13, d.y);
    atomicAdd(o + 14, d.z); atomicAdd(o + 15, d.w);
    atomicAdd(cnt + dst, 1.0f);
}

__global__ void finalize_kernel(const float* __restrict__ summed,
                                const float* __restrict__ cnt,
                                const float* __restrict__ b1,
                                const float* __restrict__ W2,
                                const float* __restrict__ b2,
                                float* __restrict__ out, int n) {
    int i = blockIdx.x * blockDim.x + threadIdx.x;
    if (i >= n) return;
    const float4* s = (const float4*)(summed + (long)i * 16);
    float4 s0 = s[0], s1 = s[1], s2 = s[2], s3 = s[3];
    float sv[16] = {s0.x, s0.y, s0.z, s0.w, s1.x, s1.y, s1.z, s1.w,
                    s2.x, s2.y, s2.z, s2.w, s3.x, s3.y, s3.z, s3.w};
    float inv = 1.0f / fmaxf(cnt[i], 1.0f);
    float acc = b2[0];
#pragma unroll
    for (int c = 0; c < 16; ++c)
        acc += W2[c] * fmaxf(sv[c] * inv + b1[c], 0.0f);
    out[i] = acc;
}

extern "C" void kernel_launch(void* const* d_in, const int* in_sizes, int n_in,
                              void* d_out, int out_size, void* d_ws, size_t ws_size,
                              hipStream_t stream) {
    const float* x  = (const float*)d_in[0];
    const void*  ei = d_in[1];
    const float* W1 = (const float*)d_in[2];
    const float* b1 = (const float*)d_in[3];
    const float* W2 = (const float*)d_in[4];
    const float* b2 = (const float*)d_in[5];
    float* out = (float*)d_out;

    float* ws = (float*)d_ws;

    // Bucket-path workspace (4B words):
    //   h2      :   800,000  (fp16 h, __half2[N][8] = 3.2 MB)
    //   packed  : 3,200,000  u32 (bucket-grouped, then node-sorted in place)
    //   btot    :      NBKT  i32 (memset 0 each call)
    //   bstart  :  NBKT + 1  i32
    //   bcursor :      NBKT  i32
    //   ndeg    :   100,000  i32
    //   nstart  :   100,000  i32
    //   bsort   :      NBKT  i32
    const size_t need_bkt =
        (size_t)(800000 + 3200000 + NBKT + (NBKT + 1) + NBKT +
                 100000 + 100000 + NBKT) * 4;

    if (ws_size >= need_bkt) {
        __half2*      h2      = (__half2*)ws;
        unsigned int* packed  = (unsigned int*)(ws + 800000);
        int*          btot    = (int*)(ws + 800000 + 3200000);
        int*          bstart  = btot + NBKT;
        int*          bcursor = bstart + NBKT + 1;
        int*          ndeg    = bcursor + NBKT;
        int*          nstart  = ndeg + N_NODES;
        int*          bsort   = nstart + N_NODES;

        hipMemsetAsync(btot, 0, NBKT * sizeof(int), stream);

        linear1_kernel<<<(N_NODES + 127) / 128, 128, 0, stream>>>(x, W1, h2, N_NODES);

        hist_kernel<<<HB, 512, 0, stream>>>(
            (const int*)ei, (const long long*)ei, btot);

        bucket_scan_kernel<<<1, 1024, 0, stream>>>(btot, bstart, bcursor);

        scatter_sort_kernel<<<EB2, 1024, 0, stream>>>(
            (const int*)ei, (const long long*)ei, bcursor, packed);

        sort_kernel<<<NBKT, 512, 0, stream>>>(packed, bstart, ndeg, nstart, bsort);

        gather_kernel<<<NBKT * 2, 512, 0, stream>>>(
            packed, ndeg, nstart, bsort, bstart, h2, b1, W2, b2, out);
    } else {
        // Fallback: R0 atomic-scatter path (13.2 MB workspace).
        float* h      = ws;                  // N_NODES * 16
        float* summed = ws + N_NODES * 16;   // N_NODES * 16
        float* cnt    = ws + N_NODES * 32;   // N_NODES
        unsigned int* flag = (unsigned int*)(ws + N_NODES * 33);

        hipMemsetAsync(summed, 0, (size_t)(N_NODES * 17) * sizeof(float), stream);
        detect_i64_kernel<<<1, 64, 0, stream>>>((const unsigned int*)ei, flag);
        linear1_f32_kernel<<<(N_NODES + 127) / 128, 128, 0, stream>>>(x, W1, h, N_NODES);
        scatter_kernel<<<(N_EDGES + 255) / 256, 256, 0, stream>>>(
            (const int*)ei, (const long long*)ei, flag, h, summed, cnt);
        finalize_kernel<<<(N_NODES + 255) / 256, 256, 0, stream>>>(
            summed, cnt, b1, W2, b2, out, N_NODES);
    }
}

// Round 12
// 99.371 us; speedup vs baseline: 1.1994x; 1.1994x over previous
//
#include <hip/hip_runtime.h>
#include <hip/hip_fp16.h>

#define N_NODES 100000
#define N_EDGES 3200000
#define NBKT 782            // buckets of 128 nodes (dst >> 7)
#define EB 512              // phase-A blocks (hist + scatter share this split)
#define EPB (N_EDGES / EB)  // 6250 edges per phase-A block
#define SCAN_BLOCK 512
#define NSCAN (NBKT * EB)   // 400384 (bucket-major counts)
#define NB_SCAN ((NSCAN + SCAN_BLOCK - 1) / SCAN_BLOCK)  // 782 (<= 1024)
#define SORT_CAP 5120       // per-bucket sorted-edge LDS capacity (20 KB)

// ---------------------------------------------------------------------------
// h2[i][c] = fp16( sum_k x[i][k] * W1[c][k] )  -- h stored as __half2[N][8]
// (3.2 MB: L2-resident per XCD)
// ---------------------------------------------------------------------------
__global__ void linear1_kernel(const float* __restrict__ x,
                               const float* __restrict__ W1,
                               __half2* __restrict__ h2, int n) {
    __shared__ float w[16 * 58];
    for (int idx = threadIdx.x; idx < 16 * 58; idx += blockDim.x)
        w[idx] = W1[idx];
    __syncthreads();

    int i = blockIdx.x * blockDim.x + threadIdx.x;
    if (i >= n) return;

    float xv[58];
    const float* xr = x + (long)i * 58;
#pragma unroll
    for (int k = 0; k < 58; ++k) xv[k] = xr[k];

    __half2 o[8];
#pragma unroll
    for (int q = 0; q < 8; ++q) {
        float a[2];
#pragma unroll
        for (int r = 0; r < 2; ++r) {
            int c = q * 2 + r;
            float acc = 0.0f;
#pragma unroll
            for (int k = 0; k < 58; ++k) acc += xv[k] * w[c * 58 + k];
            a[r] = acc;
        }
        o[q] = __floats2half2_rn(a[0], a[1]);
    }
    float4* dst = (float4*)(h2 + (long)i * 8);
    float4* src = (float4*)o;
    dst[0] = src[0];
    dst[1] = src[1];
}

// ---------------------------------------------------------------------------
// Phase A1: per-(bucket, block) histogram of dst buckets (LDS atomics only;
// deterministic bucket-major bcount writes — NO global atomics).
// Self-detects int64 vs int32 (odd 32-bit words of first 512 entries).
// ---------------------------------------------------------------------------
__global__ void __launch_bounds__(512, 8)
hist_kernel(const int* __restrict__ ei32,
            const long long* __restrict__ ei64,
            int* __restrict__ bcount) {
    __shared__ int hist[NBKT];
    __shared__ int dflag;
    int tid = threadIdx.x;
    if (tid == 0) dflag = 0;
    for (int i = tid; i < NBKT; i += 512) hist[i] = 0;
    __syncthreads();
    if (((const unsigned int*)ei32)[2 * tid + 1] != 0u) atomicOr(&dflag, 1);
    __syncthreads();
    bool i64 = (dflag == 0);

    long base = (long)blockIdx.x * EPB;
    for (int k = tid; k < EPB; k += 512) {
        long e = base + k;
        int dst = i64 ? (int)ei64[N_EDGES + e] : ei32[N_EDGES + e];
        atomicAdd(&hist[dst >> 7], 1);
    }
    __syncthreads();
    for (int b = tid; b < NBKT; b += 512)
        bcount[(long)b * EB + blockIdx.x] = hist[b];
}

// ---------------------------------------------------------------------------
// In-place exclusive scan of bcount (NSCAN entries), 3 kernels.
// ---------------------------------------------------------------------------
__global__ void scan1_kernel(int* __restrict__ data,
                             int* __restrict__ bsums, int n) {
    __shared__ int tmp[SCAN_BLOCK];
    int i = blockIdx.x * SCAN_BLOCK + threadIdx.x;
    int v = (i < n) ? data[i] : 0;
    tmp[threadIdx.x] = v;
    __syncthreads();
#pragma unroll
    for (int d = 1; d < SCAN_BLOCK; d <<= 1) {
        int t = (threadIdx.x >= d) ? tmp[threadIdx.x - d] : 0;
        __syncthreads();
        tmp[threadIdx.x] += t;
        __syncthreads();
    }
    if (i < n) data[i] = tmp[threadIdx.x] - v;  // exclusive
    if (threadIdx.x == SCAN_BLOCK - 1) bsums[blockIdx.x] = tmp[threadIdx.x];
}

// Parallel LDS exclusive scan of the (<=1024) block sums.
__global__ void scan2_kernel(int* __restrict__ bsums, int nb) {
    __shared__ int tmp[1024];
    int i = threadIdx.x;
    int v = (i < nb) ? bsums[i] : 0;
    tmp[i] = v;
    __syncthreads();
#pragma unroll
    for (int d = 1; d < 1024; d <<= 1) {
        int t = (i >= d) ? tmp[i - d] : 0;
        __syncthreads();
        tmp[i] += t;
        __syncthreads();
    }
    if (i < nb) bsums[i] = tmp[i] - v;  // exclusive
}

__global__ void scan3_kernel(int* __restrict__ data,
                             const int* __restrict__ bsums, int n) {
    int i = blockIdx.x * blockDim.x + threadIdx.x;
    if (i < n) data[i] += bsums[i / SCAN_BLOCK];
}

// ---------------------------------------------------------------------------
// Phase A2: LDS-sorted scatter (R9 structure, 2 blocks/CU occupancy).
// Counting-sort 6250 edges by dst-bucket in LDS, then stream to global in
// bucket-grouped order; offsets are the DETERMINISTIC scanned bcount.
// LDS ~51 KB -> 2 blocks/CU resident (32 waves/CU), grid 512 = 2/CU.
// ---------------------------------------------------------------------------
__global__ void __launch_bounds__(1024, 8)
scatter_sort_kernel(const int* __restrict__ ei32,
                    const long long* __restrict__ ei64,
                    const int* __restrict__ boffs,
                    unsigned int* __restrict__ packed) {
    __shared__ unsigned int vals[EPB];        // 25.0 KB bucket-grouped words
    __shared__ unsigned short bjs[EPB];       // 12.5 KB bucket id per slot
    __shared__ int hist[NBKT];
    __shared__ int curs[NBKT];
    __shared__ int gbase[NBKT];
    __shared__ int tmp[1024];
    __shared__ int dflag;

    int tid = threadIdx.x;
    if (tid == 0) dflag = 0;
    for (int i = tid; i < NBKT; i += 1024) hist[i] = 0;
    __syncthreads();
    if (tid < 512 && ((const unsigned int*)ei32)[2 * tid + 1] != 0u)
        atomicOr(&dflag, 1);
    __syncthreads();
    bool i64 = (dflag == 0);
    long base = (long)blockIdx.x * EPB;

    // pass 1: per-bucket histogram
    for (int k = tid; k < EPB; k += 1024) {
        long e = base + k;
        int dst = i64 ? (int)ei64[N_EDGES + e] : ei32[N_EDGES + e];
        atomicAdd(&hist[dst >> 7], 1);
    }
    __syncthreads();

    // 1024-wide exclusive scan (entries >= NBKT padded 0)
    int v = (tid < NBKT) ? hist[tid] : 0;
    tmp[tid] = v;
    __syncthreads();
#pragma unroll
    for (int d = 1; d < 1024; d <<= 1) {
        int t = (tid >= d) ? tmp[tid - d] : 0;
        __syncthreads();
        tmp[tid] += t;
        __syncthreads();
    }
    if (tid < NBKT) {
        int s = tmp[tid] - v;                           // local start
        curs[tid] = s;
        gbase[tid] = boffs[(long)tid * EB + blockIdx.x] - s;
    }
    __syncthreads();

    // pass 2: cursor-scatter into LDS (bucket-grouped), re-read edges (L3-hot)
    for (int k = tid; k < EPB; k += 1024) {
        long e = base + k;
        int src, dst;
        if (i64) { src = (int)ei64[e]; dst = (int)ei64[N_EDGES + e]; }
        else     { src = ei32[e];      dst = ei32[N_EDGES + e]; }
        int b = dst >> 7;
        int p = atomicAdd(&curs[b], 1);
        vals[p] = ((unsigned int)(dst & 127) << 17) | (unsigned int)src;
        bjs[p] = (unsigned short)b;
    }
    __threadfence_block();
    __syncthreads();

    // pass 3: dense-chunk copy to global
    for (int j = tid; j < EPB; j += 1024)
        packed[gbase[bjs[j]] + j] = vals[j];
}

// ---------------------------------------------------------------------------
// Phase B1: per-bucket counting sort in LDS, written BACK TO GLOBAL.
// ---------------------------------------------------------------------------
__global__ void __launch_bounds__(512, 4)
sort_kernel(unsigned int* __restrict__ packed,
            const int* __restrict__ boffs,
            int* __restrict__ ndeg,
            int* __restrict__ nstart,
            int* __restrict__ bsort) {
    __shared__ unsigned int sorted[SORT_CAP];  // 20 KB
    __shared__ int hist[128];
    __shared__ int starts[128];
    __shared__ int curs[128];
    __shared__ int tmp[512];

    int b = blockIdx.x;
    int tid = threadIdx.x;
    int start = boffs[(long)b * EB];
    int end = (b + 1 < NBKT) ? boffs[(long)(b + 1) * EB] : N_EDGES;
    int m = end - start;

    if (tid < 128) hist[tid] = 0;
    __syncthreads();

    // 1. per-node histogram
    for (int k = tid; k < m; k += 512)
        atomicAdd(&hist[(int)(packed[start + k] >> 17)], 1);
    __syncthreads();

    // 2. exclusive scan
    int v = (tid < 128) ? hist[tid] : 0;
    tmp[tid] = v;
    __syncthreads();
#pragma unroll
    for (int d = 1; d < 512; d <<= 1) {
        int t = (tid >= d) ? tmp[tid - d] : 0;
        __syncthreads();
        tmp[tid] += t;
        __syncthreads();
    }
    if (tid < 128) {
        int s = tmp[tid] - v;
        starts[tid] = s;
        curs[tid] = s;
    }
    __syncthreads();

    bool fast = (m <= SORT_CAP);   // uniform across the block
    if (fast) {
        // 3. cursor-scatter src into sorted[]
        for (int k = tid; k < m; k += 512) {
            unsigned int w = packed[start + k];
            int l = (int)(w >> 17);
            int p = atomicAdd(&curs[l], 1);
            sorted[p] = w & 0x1FFFFu;
        }
        __threadfence_block();
        __syncthreads();
        // 4. write node-sorted src list back to global (dense, coalesced)
        for (int k = tid; k < m; k += 512)
            packed[start + k] = sorted[k];
    }

    // 5. per-node meta
    if (tid < 128) {
        int g = b * 128 + tid;
        if (g < N_NODES) {
            ndeg[g] = hist[tid];
            nstart[g] = start + starts[tid];
        }
    }
    if (tid == 0) bsort[b] = fast ? 1 : 0;
}

// ---------------------------------------------------------------------------
// Phase B2: barrier-free, LDS-free gather. 8 lanes per node, each lane owns
// 2 channels; unroll-4; fused mean + bias + relu + W2-dot + b2; shfl-reduce.
// ---------------------------------------------------------------------------
__global__ void __launch_bounds__(512, 8)
gather_kernel(const unsigned int* __restrict__ packed,
              const int* __restrict__ ndeg,
              const int* __restrict__ nstart,
              const int* __restrict__ bsort,
              const int* __restrict__ boffs,
              const __half2* __restrict__ h2,
              const float* __restrict__ b1,
              const float* __restrict__ W2,
              const float* __restrict__ b2,
              float* __restrict__ out) {
    int bb = blockIdx.x;                         // 2*NBKT blocks
    int b = bb >> 1;
    int l = (bb & 1) * 64 + (threadIdx.x >> 3);  // node-in-bucket 0..127
    int c = threadIdx.x & 7;                     // channel pair 0..7
    int g = b * 128 + l;
    if (g >= N_NODES) return;                    // group-uniform; no barriers

    int deg = ndeg[g];
    float2 acc0 = {0.0f, 0.0f}, acc1 = {0.0f, 0.0f};

    if (bsort[b]) {
        int p = nstart[g], pend = p + deg;
        for (; p + 3 < pend; p += 4) {
            int sA = (int)packed[p];
            int sB = (int)packed[p + 1];
            int sC = (int)packed[p + 2];
            int sD = (int)packed[p + 3];
            float2 fA = __half22float2(h2[(long)sA * 8 + c]);
            float2 fB = __half22float2(h2[(long)sB * 8 + c]);
            float2 fC = __half22float2(h2[(long)sC * 8 + c]);
            float2 fD = __half22float2(h2[(long)sD * 8 + c]);
            acc0.x += fA.x + fC.x; acc0.y += fA.y + fC.y;
            acc1.x += fB.x + fD.x; acc1.y += fB.y + fD.y;
        }
        for (; p < pend; ++p) {
            float2 f = __half22float2(h2[(long)packed[p] * 8 + c]);
            acc0.x += f.x; acc0.y += f.y;
        }
    } else {
        // never-expected universal fallback: filter-scan the whole bucket
        int bs = boffs[(long)b * EB];
        int be = (b + 1 < NBKT) ? boffs[(long)(b + 1) * EB] : N_EDGES;
        for (int p = bs; p < be; ++p) {
            unsigned int w = packed[p];
            if ((int)(w >> 17) == l) {
                float2 f = __half22float2(h2[(long)(w & 0x1FFFFu) * 8 + c]);
                acc0.x += f.x; acc0.y += f.y;
            }
        }
    }

    float inv = 1.0f / fmaxf((float)deg, 1.0f);
    float sx = acc0.x + acc1.x, sy = acc0.y + acc1.y;
    float v = fmaxf(sx * inv + b1[2 * c], 0.0f)     * W2[2 * c]
            + fmaxf(sy * inv + b1[2 * c + 1], 0.0f) * W2[2 * c + 1];
    v += __shfl_xor(v, 1);
    v += __shfl_xor(v, 2);
    v += __shfl_xor(v, 4);
    if (c == 0) out[g] = v + b2[0];
}

// ---------------------------------------------------------------------------
// Fallback path (R0): atomic value scatter + finalize. Used if ws too small.
// ---------------------------------------------------------------------------
__global__ void detect_i64_kernel(const unsigned int* __restrict__ ei,
                                  unsigned int* __restrict__ flag) {
    unsigned int v = 0;
    int lane = threadIdx.x;  // 64 threads
    for (int j = lane; j < 512; j += 64) v |= ei[2 * j + 1];
    unsigned long long any_nonzero = __ballot(v != 0u);
    if (lane == 0) *flag = (any_nonzero == 0ULL) ? 1u : 0u;
}

__global__ void linear1_f32_kernel(const float* __restrict__ x,
                                   const float* __restrict__ W1,
                                   float* __restrict__ h, int n) {
    __shared__ float w[16 * 58];
    for (int idx = threadIdx.x; idx < 16 * 58; idx += blockDim.x)
        w[idx] = W1[idx];
    __syncthreads();
    int i = blockIdx.x * blockDim.x + threadIdx.x;
    if (i >= n) return;
    float xv[58];
    const float* xr = x + (long)i * 58;
#pragma unroll
    for (int k = 0; k < 58; ++k) xv[k] = xr[k];
#pragma unroll
    for (int cq = 0; cq < 4; ++cq) {
        float a[4];
#pragma unroll
        for (int r = 0; r < 4; ++r) {
            int ch = cq * 4 + r;
            float acc = 0.0f;
#pragma unroll
            for (int k = 0; k < 58; ++k) acc += xv[k] * w[ch * 58 + k];
            a[r] = acc;
        }
        ((float4*)(h + (long)i * 16))[cq] = make_float4(a[0], a[1], a[2], a[3]);
    }
}

__global__ void scatter_kernel(const int* __restrict__ ei32,
                               const long long* __restrict__ ei64,
                               const unsigned int* __restrict__ flag,
                               const float* __restrict__ h,
                               float* __restrict__ summed,
                               float* __restrict__ cnt) {
    long e = (long)blockIdx.x * blockDim.x + threadIdx.x;
    if (e >= N_EDGES) return;
    long src, dst;
    if (*flag) { src = (long)ei64[e]; dst = (long)ei64[N_EDGES + e]; }
    else       { src = (long)ei32[e]; dst = (long)ei32[N_EDGES + e]; }
    const float4* hs = (const float4*)(h + src * 16);
    float4 a = hs[0], b = hs[1], c = hs[2], d = hs[3];
    float* o = summed + dst * 16;
    atomicAdd(o + 0,  a.x); atomicAdd(o + 1,  a.y);
    atomicAdd(o + 2,  a.z); atomicAdd(o + 3,  a.w);
    atomicAdd(o + 4,  b.x); atomicAdd(o + 5,  b.y);
    atomicAdd(o + 6,  b.z); atomicAdd(o + 7,  b.w);
    atomicAdd(o + 8,  c.x); atomicAdd(o + 9,  c.y);
    atomicAdd(o + 10, c.z); atomicAdd(o + 11, c.w);
    atomicAdd(o + 12, d.x); atomicAdd(o + 13, d.y);
    atomicAdd(o + 14, d.z); atomicAdd(o + 15, d.w);
    atomicAdd(cnt + dst, 1.0f);
}

__global__ void finalize_kernel(const float* __restrict__ summed,
                                const float* __restrict__ cnt,
                                const float* __restrict__ b1,
                                const float* __restrict__ W2,
                                const float* __restrict__ b2,
                                float* __restrict__ out, int n) {
    int i = blockIdx.x * blockDim.x + threadIdx.x;
    if (i >= n) return;
    const float4* s = (const float4*)(summed + (long)i * 16);
    float4 s0 = s[0], s1 = s[1], s2 = s[2], s3 = s[3];
    float sv[16] = {s0.x, s0.y, s0.z, s0.w, s1.x, s1.y, s1.z, s1.w,
                    s2.x, s2.y, s2.z, s2.w, s3.x, s3.y, s3.z, s3.w};
    float inv = 1.0f / fmaxf(cnt[i], 1.0f);
    float acc = b2[0];
#pragma unroll
    for (int c = 0; c < 16; ++c)
        acc += W2[c] * fmaxf(sv[c] * inv + b1[c], 0.0f);
    out[i] = acc;
}

extern "C" void kernel_launch(void* const* d_in, const int* in_sizes, int n_in,
                              void* d_out, int out_size, void* d_ws, size_t ws_size,
                              hipStream_t stream) {
    const float* x  = (const float*)d_in[0];
    const void*  ei = d_in[1];
    const float* W1 = (const float*)d_in[2];
    const float* b1 = (const float*)d_in[3];
    const float* W2 = (const float*)d_in[4];
    const float* b2 = (const float*)d_in[5];
    float* out = (float*)d_out;

    float* ws = (float*)d_ws;

    // Bucket-path workspace (4B words):
    //   h2     :   800,000  (fp16 h, __half2[N][8] = 3.2 MB)
    //   packed : 3,200,000  u32 (bucket-grouped, then node-sorted in place)
    //   bcount :   NSCAN    i32 (400,384; scanned in place -> offsets)
    //   bsums  :     1,024  i32
    //   ndeg   :   100,000  i32
    //   nstart :   100,000  i32
    //   bsort  :      NBKT  i32
    const size_t need_bkt =
        (size_t)(800000 + 3200000 + NSCAN + 1024 + 100000 + 100000 + NBKT) * 4;

    if (ws_size >= need_bkt) {
        __half2*      h2     = (__half2*)ws;
        unsigned int* packed = (unsigned int*)(ws + 800000);
        int*          bcount = (int*)(ws + 800000 + 3200000);
        int*          bsums  = bcount + NSCAN;
        int*          ndeg   = bsums + 1024;
        int*          nstart = ndeg + N_NODES;
        int*          bsort  = nstart + N_NODES;

        linear1_kernel<<<(N_NODES + 127) / 128, 128, 0, stream>>>(x, W1, h2, N_NODES);

        hist_kernel<<<EB, 512, 0, stream>>>(
            (const int*)ei, (const long long*)ei, bcount);

        scan1_kernel<<<NB_SCAN, SCAN_BLOCK, 0, stream>>>(bcount, bsums, NSCAN);
        scan2_kernel<<<1, 1024, 0, stream>>>(bsums, NB_SCAN);
        scan3_kernel<<<(NSCAN + 255) / 256, 256, 0, stream>>>(bcount, bsums, NSCAN);

        scatter_sort_kernel<<<EB, 1024, 0, stream>>>(
            (const int*)ei, (const long long*)ei, bcount, packed);

        sort_kernel<<<NBKT, 512, 0, stream>>>(packed, bcount, ndeg, nstart, bsort);

        gather_kernel<<<NBKT * 2, 512, 0, stream>>>(
            packed, ndeg, nstart, bsort, bcount, h2, b1, W2, b2, out);
    } else {
        // Fallback: R0 atomic-scatter path (13.2 MB workspace).
        float* h      = ws;                  // N_NODES * 16
        float* summed = ws + N_NODES * 16;   // N_NODES * 16
        float* cnt    = ws + N_NODES * 32;   // N_NODES
        unsigned int* flag = (unsigned int*)(ws + N_NODES * 33);

        hipMemsetAsync(summed, 0, (size_t)(N_NODES * 17) * sizeof(float), stream);
        detect_i64_kernel<<<1, 64, 0, stream>>>((const unsigned int*)ei, flag);
        linear1_f32_kernel<<<(N_NODES + 127) / 128, 128, 0, stream>>>(x, W1, h, N_NODES);
        scatter_kernel<<<(N_EDGES + 255) / 256, 256, 0, stream>>>(
            (const int*)ei, (const long long*)ei, flag, h, summed, cnt);
        finalize_kernel<<<(N_NODES + 255) / 256, 256, 0, stream>>>(
            summed, cnt, b1, W2, b2, out, N_NODES);
    }
}

// Round 13
// 92.326 us; speedup vs baseline: 1.2909x; 1.0763x over previous
//
#include <hip/hip_runtime.h>
#include <hip/hip_fp16.h>

#define N_NODES 100000
#define N_EDGES 3200000
#define NBKT 782            // buckets of 128 nodes (dst >> 7)
#define EB 512              // phase-A blocks (hist + scatter share this split)
#define EPB (N_EDGES / EB)  // 6250 edges per phase-A block
#define SCAN_BLOCK 512
#define NSCAN (NBKT * EB)   // 400384 (bucket-major counts)
#define NB_SCAN ((NSCAN + SCAN_BLOCK - 1) / SCAN_BLOCK)  // 782 (<= 1024)
#define SORT_CAP 5120       // per-bucket sorted-edge LDS capacity (20 KB)
#define LIN_BLOCKS ((N_NODES + 511) / 512)  // 196 linear-path blocks

// off(idx) = bcount[idx] + bsums[idx >> 9]  (scan1 local prefix + scan2 base)

// ---------------------------------------------------------------------------
// Fused phase A0+A1: blocks [0, LIN_BLOCKS) compute h2 = fp16(x @ W1^T);
// blocks [LIN_BLOCKS, LIN_BLOCKS+EB) histogram dst buckets (LDS atomics,
// deterministic bucket-major bcount writes). Both paths block-uniform.
// Hist path self-detects int64 vs int32 (odd 32-bit words of first 512).
// ---------------------------------------------------------------------------
__global__ void lin_hist_kernel(const float* __restrict__ x,
                                const float* __restrict__ W1,
                                __half2* __restrict__ h2,
                                const int* __restrict__ ei32,
                                const long long* __restrict__ ei64,
                                int* __restrict__ bcount) {
    __shared__ float w[16 * 58];
    __shared__ int hist[NBKT];
    __shared__ int dflag;
    int tid = threadIdx.x;

    if (blockIdx.x < LIN_BLOCKS) {
        // ---- linear1 path ----
        for (int idx = tid; idx < 16 * 58; idx += 512) w[idx] = W1[idx];
        __syncthreads();

        int i = blockIdx.x * 512 + tid;
        if (i >= N_NODES) return;

        float xv[58];
        const float* xr = x + (long)i * 58;
#pragma unroll
        for (int k = 0; k < 58; ++k) xv[k] = xr[k];

        __half2 o[8];
#pragma unroll
        for (int q = 0; q < 8; ++q) {
            float a[2];
#pragma unroll
            for (int r = 0; r < 2; ++r) {
                int c = q * 2 + r;
                float acc = 0.0f;
#pragma unroll
                for (int k = 0; k < 58; ++k) acc += xv[k] * w[c * 58 + k];
                a[r] = acc;
            }
            o[q] = __floats2half2_rn(a[0], a[1]);
        }
        float4* dst = (float4*)(h2 + (long)i * 8);
        float4* src = (float4*)o;
        dst[0] = src[0];
        dst[1] = src[1];
    } else {
        // ---- hist path ----
        int blk = blockIdx.x - LIN_BLOCKS;
        if (tid == 0) dflag = 0;
        for (int i = tid; i < NBKT; i += 512) hist[i] = 0;
        __syncthreads();
        if (((const unsigned int*)ei32)[2 * tid + 1] != 0u) atomicOr(&dflag, 1);
        __syncthreads();
        bool i64 = (dflag == 0);

        long base = (long)blk * EPB;
        for (int k = tid; k < EPB; k += 512) {
            long e = base + k;
            int dst = i64 ? (int)ei64[N_EDGES + e] : ei32[N_EDGES + e];
            atomicAdd(&hist[dst >> 7], 1);
        }
        __syncthreads();
        for (int b = tid; b < NBKT; b += 512)
            bcount[(long)b * EB + blk] = hist[b];
    }
}

// ---------------------------------------------------------------------------
// scan1: block-local exclusive scan of bcount in place + block totals.
// scan2: exclusive scan of the (<=1024) block totals in place.
// Consumers add bsums[idx>>9] inline (no scan3 pass).
// ---------------------------------------------------------------------------
__global__ void scan1_kernel(int* __restrict__ data,
                             int* __restrict__ bsums, int n) {
    __shared__ int tmp[SCAN_BLOCK];
    int i = blockIdx.x * SCAN_BLOCK + threadIdx.x;
    int v = (i < n) ? data[i] : 0;
    tmp[threadIdx.x] = v;
    __syncthreads();
#pragma unroll
    for (int d = 1; d < SCAN_BLOCK; d <<= 1) {
        int t = (threadIdx.x >= d) ? tmp[threadIdx.x - d] : 0;
        __syncthreads();
        tmp[threadIdx.x] += t;
        __syncthreads();
    }
    if (i < n) data[i] = tmp[threadIdx.x] - v;  // exclusive (block-local)
    if (threadIdx.x == SCAN_BLOCK - 1) bsums[blockIdx.x] = tmp[threadIdx.x];
}

__global__ void scan2_kernel(int* __restrict__ bsums, int nb) {
    __shared__ int tmp[1024];
    int i = threadIdx.x;
    int v = (i < nb) ? bsums[i] : 0;
    tmp[i] = v;
    __syncthreads();
#pragma unroll
    for (int d = 1; d < 1024; d <<= 1) {
        int t = (i >= d) ? tmp[i - d] : 0;
        __syncthreads();
        tmp[i] += t;
        __syncthreads();
    }
    if (i < nb) bsums[i] = tmp[i] - v;  // exclusive
}

// ---------------------------------------------------------------------------
// Phase A2: LDS-sorted scatter. Pass 1 reads dst once (cached in LDS) +
// histogram; pass 2 reads only src from global; pass 3 streams out in
// bucket-grouped dense order. Offsets = deterministic scanned bcount.
// LDS ~76 KB -> 2 blocks/CU (152 KB of 160).
// ---------------------------------------------------------------------------
__global__ void __launch_bounds__(1024, 8)
scatter_sort_kernel(const int* __restrict__ ei32,
                    const long long* __restrict__ ei64,
                    const int* __restrict__ bcount,
                    const int* __restrict__ bsums,
                    unsigned int* __restrict__ packed) {
    __shared__ unsigned int vals[EPB];        // 25.0 KB bucket-grouped words
    __shared__ unsigned int dstin[EPB];       // 25.0 KB cached dst per slot
    __shared__ unsigned short bjs[EPB];       // 12.5 KB bucket id per slot
    __shared__ int hist[NBKT];
    __shared__ int curs[NBKT];
    __shared__ int gbase[NBKT];
    __shared__ int tmp[1024];
    __shared__ int dflag;

    int tid = threadIdx.x;
    if (tid == 0) dflag = 0;
    for (int i = tid; i < NBKT; i += 1024) hist[i] = 0;
    __syncthreads();
    if (tid < 512 && ((const unsigned int*)ei32)[2 * tid + 1] != 0u)
        atomicOr(&dflag, 1);
    __syncthreads();
    bool i64 = (dflag == 0);
    long base = (long)blockIdx.x * EPB;

    // pass 1: read dst once -> LDS cache + per-bucket histogram
    for (int k = tid; k < EPB; k += 1024) {
        long e = base + k;
        int dst = i64 ? (int)ei64[N_EDGES + e] : ei32[N_EDGES + e];
        dstin[k] = (unsigned int)dst;
        atomicAdd(&hist[dst >> 7], 1);
    }
    __syncthreads();

    // 1024-wide exclusive scan (entries >= NBKT padded 0)
    int v = (tid < NBKT) ? hist[tid] : 0;
    tmp[tid] = v;
    __syncthreads();
#pragma unroll
    for (int d = 1; d < 1024; d <<= 1) {
        int t = (tid >= d) ? tmp[tid - d] : 0;
        __syncthreads();
        tmp[tid] += t;
        __syncthreads();
    }
    if (tid < NBKT) {
        int s = tmp[tid] - v;                 // local start
        long gi = (long)tid * EB + blockIdx.x;
        curs[tid] = s;
        gbase[tid] = bcount[gi] + bsums[gi >> 9] - s;
    }
    __syncthreads();

    // pass 2: src from global (first touch), dst from LDS; cursor-scatter
    for (int k = tid; k < EPB; k += 1024) {
        long e = base + k;
        int src = i64 ? (int)ei64[e] : ei32[e];
        unsigned int dst = dstin[k];
        int b = (int)(dst >> 7);
        int p = atomicAdd(&curs[b], 1);
        vals[p] = ((dst & 127u) << 17) | (unsigned int)src;
        bjs[p] = (unsigned short)b;
    }
    __threadfence_block();
    __syncthreads();

    // pass 3: dense-chunk copy to global
    for (int j = tid; j < EPB; j += 1024)
        packed[gbase[bjs[j]] + j] = vals[j];
}

// ---------------------------------------------------------------------------
// Phase B1: per-bucket counting sort. packed read ONCE into LDS (raw[]),
// histogram/scatter from LDS, node-sorted result written back to global.
// LDS ~43.5 KB -> 3 blocks/CU.
// ---------------------------------------------------------------------------
__global__ void __launch_bounds__(512, 6)
sort_kernel(unsigned int* __restrict__ packed,
            const int* __restrict__ bcount,
            const int* __restrict__ bsums,
            int* __restrict__ ndeg,
            int* __restrict__ nstart,
            int* __restrict__ bsort) {
    __shared__ unsigned int raw[SORT_CAP];     // 20 KB staged input
    __shared__ unsigned int sorted[SORT_CAP];  // 20 KB node-grouped output
    __shared__ int hist[128];
    __shared__ int starts[128];
    __shared__ int curs[128];
    __shared__ int tmp[512];

    int b = blockIdx.x;
    int tid = threadIdx.x;
    long gi = (long)b * EB;
    int start = bcount[gi] + bsums[gi >> 9];
    int end;
    if (b + 1 < NBKT) {
        long gj = (long)(b + 1) * EB;
        end = bcount[gj] + bsums[gj >> 9];
    } else {
        end = N_EDGES;
    }
    int m = end - start;
    bool fast = (m <= SORT_CAP);   // uniform across the block

    if (tid < 128) hist[tid] = 0;
    __syncthreads();

    if (fast) {
        // 0. stage raw words (single global read of this bucket)
        for (int k = tid; k < m; k += 512) raw[k] = packed[start + k];
        __syncthreads();

        // 1. per-node histogram from LDS
        for (int k = tid; k < m; k += 512)
            atomicAdd(&hist[(int)(raw[k] >> 17)], 1);
    } else {
        // never-expected: histogram from global
        for (int k = tid; k < m; k += 512)
            atomicAdd(&hist[(int)(packed[start + k] >> 17)], 1);
    }
    __syncthreads();

    // 2. exclusive scan (512-wide, entries >=128 padded 0)
    int v = (tid < 128) ? hist[tid] : 0;
    tmp[tid] = v;
    __syncthreads();
#pragma unroll
    for (int d = 1; d < 512; d <<= 1) {
        int t = (tid >= d) ? tmp[tid - d] : 0;
        __syncthreads();
        tmp[tid] += t;
        __syncthreads();
    }
    if (tid < 128) {
        int s = tmp[tid] - v;
        starts[tid] = s;
        curs[tid] = s;
    }
    __syncthreads();

    if (fast) {
        // 3. cursor-scatter src into sorted[] (LDS -> LDS)
        for (int k = tid; k < m; k += 512) {
            unsigned int w = raw[k];
            int l = (int)(w >> 17);
            int p = atomicAdd(&curs[l], 1);
            sorted[p] = w & 0x1FFFFu;
        }
        __threadfence_block();
        __syncthreads();
        // 4. write node-sorted src list back to global (dense, coalesced)
        for (int k = tid; k < m; k += 512)
            packed[start + k] = sorted[k];
    }

    // 5. per-node meta
    if (tid < 128) {
        int g = b * 128 + tid;
        if (g < N_NODES) {
            ndeg[g] = hist[tid];
            nstart[g] = start + starts[tid];
        }
    }
    if (tid == 0) bsort[b] = fast ? 1 : 0;
}

// ---------------------------------------------------------------------------
// Phase B2: barrier-free, LDS-free gather. 8 lanes per node, each lane owns
// 2 channels; unroll-4; fused mean + bias + relu + W2-dot + b2; shfl-reduce.
// ---------------------------------------------------------------------------
__global__ void __launch_bounds__(512, 8)
gather_kernel(const unsigned int* __restrict__ packed,
              const int* __restrict__ ndeg,
              const int* __restrict__ nstart,
              const int* __restrict__ bsort,
              const int* __restrict__ bcount,
              const int* __restrict__ bsums,
              const __half2* __restrict__ h2,
              const float* __restrict__ b1,
              const float* __restrict__ W2,
              const float* __restrict__ b2,
              float* __restrict__ out) {
    int bb = blockIdx.x;                         // 2*NBKT blocks
    int b = bb >> 1;
    int l = (bb & 1) * 64 + (threadIdx.x >> 3);  // node-in-bucket 0..127
    int c = threadIdx.x & 7;                     // channel pair 0..7
    int g = b * 128 + l;
    if (g >= N_NODES) return;                    // group-uniform; no barriers

    int deg = ndeg[g];
    float2 acc0 = {0.0f, 0.0f}, acc1 = {0.0f, 0.0f};

    if (bsort[b]) {
        int p = nstart[g], pend = p + deg;
        for (; p + 3 < pend; p += 4) {
            int sA = (int)packed[p];
            int sB = (int)packed[p + 1];
            int sC = (int)packed[p + 2];
            int sD = (int)packed[p + 3];
            float2 fA = __half22float2(h2[(long)sA * 8 + c]);
            float2 fB = __half22float2(h2[(long)sB * 8 + c]);
            float2 fC = __half22float2(h2[(long)sC * 8 + c]);
            float2 fD = __half22float2(h2[(long)sD * 8 + c]);
            acc0.x += fA.x + fC.x; acc0.y += fA.y + fC.y;
            acc1.x += fB.x + fD.x; acc1.y += fB.y + fD.y;
        }
        for (; p < pend; ++p) {
            float2 f = __half22float2(h2[(long)packed[p] * 8 + c]);
            acc0.x += f.x; acc0.y += f.y;
        }
    } else {
        // never-expected universal fallback: filter-scan the whole bucket
        long gi = (long)b * EB;
        int bs = bcount[gi] + bsums[gi >> 9];
        int be;
        if (b + 1 < NBKT) {
            long gj = (long)(b + 1) * EB;
            be = bcount[gj] + bsums[gj >> 9];
        } else {
            be = N_EDGES;
        }
        for (int p = bs; p < be; ++p) {
            unsigned int w = packed[p];
            if ((int)(w >> 17) == l) {
                float2 f = __half22float2(h2[(long)(w & 0x1FFFFu) * 8 + c]);
                acc0.x += f.x; acc0.y += f.y;
            }
        }
    }

    float inv = 1.0f / fmaxf((float)deg, 1.0f);
    float sx = acc0.x + acc1.x, sy = acc0.y + acc1.y;
    float v = fmaxf(sx * inv + b1[2 * c], 0.0f)     * W2[2 * c]
            + fmaxf(sy * inv + b1[2 * c + 1], 0.0f) * W2[2 * c + 1];
    v += __shfl_xor(v, 1);
    v += __shfl_xor(v, 2);
    v += __shfl_xor(v, 4);
    if (c == 0) out[g] = v + b2[0];
}

// ---------------------------------------------------------------------------
// Fallback path (R0): atomic value scatter + finalize. Used if ws too small.
// ---------------------------------------------------------------------------
__global__ void detect_i64_kernel(const unsigned int* __restrict__ ei,
                                  unsigned int* __restrict__ flag) {
    unsigned int v = 0;
    int lane = threadIdx.x;  // 64 threads
    for (int j = lane; j < 512; j += 64) v |= ei[2 * j + 1];
    unsigned long long any_nonzero = __ballot(v != 0u);
    if (lane == 0) *flag = (any_nonzero == 0ULL) ? 1u : 0u;
}

__global__ void linear1_f32_kernel(const float* __restrict__ x,
                                   const float* __restrict__ W1,
                                   float* __restrict__ h, int n) {
    __shared__ float w[16 * 58];
    for (int idx = threadIdx.x; idx < 16 * 58; idx += blockDim.x)
        w[idx] = W1[idx];
    __syncthreads();
    int i = blockIdx.x * blockDim.x + threadIdx.x;
    if (i >= n) return;
    float xv[58];
    const float* xr = x + (long)i * 58;
#pragma unroll
    for (int k = 0; k < 58; ++k) xv[k] = xr[k];
#pragma unroll
    for (int cq = 0; cq < 4; ++cq) {
        float a[4];
#pragma unroll
        for (int r = 0; r < 4; ++r) {
            int ch = cq * 4 + r;
            float acc = 0.0f;
#pragma unroll
            for (int k = 0; k < 58; ++k) acc += xv[k] * w[ch * 58 + k];
            a[r] = acc;
        }
        ((float4*)(h + (long)i * 16))[cq] = make_float4(a[0], a[1], a[2], a[3]);
    }
}

__global__ void scatter_kernel(const int* __restrict__ ei32,
                               const long long* __restrict__ ei64,
                               const unsigned int* __restrict__ flag,
                               const float* __restrict__ h,
                               float* __restrict__ summed,
                               float* __restrict__ cnt) {
    long e = (long)blockIdx.x * blockDim.x + threadIdx.x;
    if (e >= N_EDGES) return;
    long src, dst;
    if (*flag) { src = (long)ei64[e]; dst = (long)ei64[N_EDGES + e]; }
    else       { src = (long)ei32[e]; dst = (long)ei32[N_EDGES + e]; }
    const float4* hs = (const float4*)(h + src * 16);
    float4 a = hs[0], b = hs[1], c = hs[2], d = hs[3];
    float* o = summed + dst * 16;
    atomicAdd(o + 0,  a.x); atomicAdd(o + 1,  a.y);
    atomicAdd(o + 2,  a.z); atomicAdd(o + 3,  a.w);
    atomicAdd(o + 4,  b.x); atomicAdd(o + 5,  b.y);
    atomicAdd(o + 6,  b.z); atomicAdd(o + 7,  b.w);
    atomicAdd(o + 8,  c.x); atomicAdd(o + 9,  c.y);
    atomicAdd(o + 10, c.z); atomicAdd(o + 11, c.w);
    atomicAdd(o + 12, d.x); atomicAdd(o + 13, d.y);
    atomicAdd(o + 14, d.z); atomicAdd(o + 15, d.w);
    atomicAdd(cnt + dst, 1.0f);
}

__global__ void finalize_kernel(const float* __restrict__ summed,
                                const float* __restrict__ cnt,
                                const float* __restrict__ b1,
                                const float* __restrict__ W2,
                                const float* __restrict__ b2,
                                float* __restrict__ out, int n) {
    int i = blockIdx.x * blockDim.x + threadIdx.x;
    if (i >= n) return;
    const float4* s = (const float4*)(summed + (long)i * 16);
    float4 s0 = s[0], s1 = s[1], s2 = s[2], s3 = s[3];
    float sv[16] = {s0.x, s0.y, s0.z, s0.w, s1.x, s1.y, s1.z, s1.w,
                    s2.x, s2.y, s2.z, s2.w, s3.x, s3.y, s3.z, s3.w};
    float inv = 1.0f / fmaxf(cnt[i], 1.0f);
    float acc = b2[0];
#pragma unroll
    for (int c = 0; c < 16; ++c)
        acc += W2[c] * fmaxf(sv[c] * inv + b1[c], 0.0f);
    out[i] = acc;
}

extern "C" void kernel_launch(void* const* d_in, const int* in_sizes, int n_in,
                              void* d_out, int out_size, void* d_ws, size_t ws_size,
                              hipStream_t stream) {
    const float* x  = (const float*)d_in[0];
    const void*  ei = d_in[1];
    const float* W1 = (const float*)d_in[2];
    const float* b1 = (const float*)d_in[3];
    const float* W2 = (const float*)d_in[4];
    const float* b2 = (const float*)d_in[5];
    float* out = (float*)d_out;

    float* ws = (float*)d_ws;

    // Bucket-path workspace (4B words):
    //   h2     :   800,000  (fp16 h, __half2[N][8] = 3.2 MB)
    //   packed : 3,200,000  u32 (bucket-grouped, then node-sorted in place)
    //   bcount :   NSCAN    i32 (400,384; block-local prefix after scan1)
    //   bsums  :     1,024  i32 (scan2 base offsets)
    //   ndeg   :   100,000  i32
    //   nstart :   100,000  i32
    //   bsort  :      NBKT  i32
    const size_t need_bkt =
        (size_t)(800000 + 3200000 + NSCAN + 1024 + 100000 + 100000 + NBKT) * 4;

    if (ws_size >= need_bkt) {
        __half2*      h2     = (__half2*)ws;
        unsigned int* packed = (unsigned int*)(ws + 800000);
        int*          bcount = (int*)(ws + 800000 + 3200000);
        int*          bsums  = bcount + NSCAN;
        int*          ndeg   = bsums + 1024;
        int*          nstart = ndeg + N_NODES;
        int*          bsort  = nstart + N_NODES;

        lin_hist_kernel<<<LIN_BLOCKS + EB, 512, 0, stream>>>(
            x, W1, h2, (const int*)ei, (const long long*)ei, bcount);

        scan1_kernel<<<NB_SCAN, SCAN_BLOCK, 0, stream>>>(bcount, bsums, NSCAN);
        scan2_kernel<<<1, 1024, 0, stream>>>(bsums, NB_SCAN);

        scatter_sort_kernel<<<EB, 1024, 0, stream>>>(
            (const int*)ei, (const long long*)ei, bcount, bsums, packed);

        sort_kernel<<<NBKT, 512, 0, stream>>>(
            packed, bcount, bsums, ndeg, nstart, bsort);

        gather_kernel<<<NBKT * 2, 512, 0, stream>>>(
            packed, ndeg, nstart, bsort, bcount, bsums, h2, b1, W2, b2, out);
    } else {
        // Fallback: R0 atomic-scatter path (13.2 MB workspace).
        float* h      = ws;                  // N_NODES * 16
        float* summed = ws + N_NODES * 16;   // N_NODES * 16
        float* cnt    = ws + N_NODES * 32;   // N_NODES
        unsigned int* flag = (unsigned int*)(ws + N_NODES * 33);

        hipMemsetAsync(summed, 0, (size_t)(N_NODES * 17) * sizeof(float), stream);
        detect_i64_kernel<<<1, 64, 0, stream>>>((const unsigned int*)ei, flag);
        linear1_f32_kernel<<<(N_NODES + 127) / 128, 128, 0, stream>>>(x, W1, h, N_NODES);
        scatter_kernel<<<(N_EDGES + 255) / 256, 256, 0, stream>>>(
            (const int*)ei, (const long long*)ei, flag, h, summed, cnt);
        finalize_kernel<<<(N_NODES + 255) / 256, 256, 0, stream>>>(
            summed, cnt, b1, W2, b2, out, N_NODES);
    }
}

// Round 14
// 77.605 us; speedup vs baseline: 1.5358x; 1.1897x over previous
//
#include <hip/hip_runtime.h>
#include <hip/hip_fp16.h>

#define N_NODES 100000
#define N_EDGES 3200000
#define NBKT 782            // buckets of 128 nodes (dst >> 7)
#define EB 512              // phase-A blocks (hist + scatter share this split)
#define EPB (N_EDGES / EB)  // 6250 edges per phase-A block
#define SCAN_BLOCK 512
#define NSCAN (NBKT * EB)   // 400384 (bucket-major counts)
#define NB_SCAN ((NSCAN + SCAN_BLOCK - 1) / SCAN_BLOCK)  // 782 (<= 1024)
#define SORT_CAP 5120       // per-bucket sorted-edge LDS capacity (20 KB)
#define LIN_BLOCKS ((N_NODES + 511) / 512)  // 196 linear-path blocks

// off(idx) = bcount[idx] + bsums[idx >> 9]  (scan1 local prefix + scan2 base)

// ---------------------------------------------------------------------------
// Fused phase A0+A1: blocks [0, LIN_BLOCKS) compute h2 = fp16(x @ W1^T);
// blocks [LIN_BLOCKS, LIN_BLOCKS+EB) histogram dst buckets (LDS atomics,
// deterministic bucket-major bcount writes). Both paths block-uniform.
// Hist path self-detects int64 vs int32 (odd 32-bit words of first 512).
// ---------------------------------------------------------------------------
__global__ void lin_hist_kernel(const float* __restrict__ x,
                                const float* __restrict__ W1,
                                __half2* __restrict__ h2,
                                const int* __restrict__ ei32,
                                const long long* __restrict__ ei64,
                                int* __restrict__ bcount) {
    __shared__ float w[16 * 58];
    __shared__ int hist[NBKT];
    __shared__ int dflag;
    int tid = threadIdx.x;

    if (blockIdx.x < LIN_BLOCKS) {
        // ---- linear1 path ----
        for (int idx = tid; idx < 16 * 58; idx += 512) w[idx] = W1[idx];
        __syncthreads();

        int i = blockIdx.x * 512 + tid;
        if (i >= N_NODES) return;

        float xv[58];
        const float* xr = x + (long)i * 58;
#pragma unroll
        for (int k = 0; k < 58; ++k) xv[k] = xr[k];

        __half2 o[8];
#pragma unroll
        for (int q = 0; q < 8; ++q) {
            float a[2];
#pragma unroll
            for (int r = 0; r < 2; ++r) {
                int c = q * 2 + r;
                float acc = 0.0f;
#pragma unroll
                for (int k = 0; k < 58; ++k) acc += xv[k] * w[c * 58 + k];
                a[r] = acc;
            }
            o[q] = __floats2half2_rn(a[0], a[1]);
        }
        float4* dst = (float4*)(h2 + (long)i * 8);
        float4* src = (float4*)o;
        dst[0] = src[0];
        dst[1] = src[1];
    } else {
        // ---- hist path ----
        int blk = blockIdx.x - LIN_BLOCKS;
        if (tid == 0) dflag = 0;
        for (int i = tid; i < NBKT; i += 512) hist[i] = 0;
        __syncthreads();
        if (((const unsigned int*)ei32)[2 * tid + 1] != 0u) atomicOr(&dflag, 1);
        __syncthreads();
        bool i64 = (dflag == 0);

        long base = (long)blk * EPB;
        for (int k = tid; k < EPB; k += 512) {
            long e = base + k;
            int dst = i64 ? (int)ei64[N_EDGES + e] : ei32[N_EDGES + e];
            atomicAdd(&hist[dst >> 7], 1);
        }
        __syncthreads();
        for (int b = tid; b < NBKT; b += 512)
            bcount[(long)b * EB + blk] = hist[b];
    }
}

// ---------------------------------------------------------------------------
// scan1: block-local exclusive scan of bcount in place + block totals.
// scan2: exclusive scan of the (<=1024) block totals in place.
// Consumers add bsums[idx>>9] inline (no scan3 pass).
// ---------------------------------------------------------------------------
__global__ void scan1_kernel(int* __restrict__ data,
                             int* __restrict__ bsums, int n) {
    __shared__ int tmp[SCAN_BLOCK];
    int i = blockIdx.x * SCAN_BLOCK + threadIdx.x;
    int v = (i < n) ? data[i] : 0;
    tmp[threadIdx.x] = v;
    __syncthreads();
#pragma unroll
    for (int d = 1; d < SCAN_BLOCK; d <<= 1) {
        int t = (threadIdx.x >= d) ? tmp[threadIdx.x - d] : 0;
        __syncthreads();
        tmp[threadIdx.x] += t;
        __syncthreads();
    }
    if (i < n) data[i] = tmp[threadIdx.x] - v;  // exclusive (block-local)
    if (threadIdx.x == SCAN_BLOCK - 1) bsums[blockIdx.x] = tmp[threadIdx.x];
}

__global__ void scan2_kernel(int* __restrict__ bsums, int nb) {
    __shared__ int tmp[1024];
    int i = threadIdx.x;
    int v = (i < nb) ? bsums[i] : 0;
    tmp[i] = v;
    __syncthreads();
#pragma unroll
    for (int d = 1; d < 1024; d <<= 1) {
        int t = (i >= d) ? tmp[i - d] : 0;
        __syncthreads();
        tmp[i] += t;
        __syncthreads();
    }
    if (i < nb) bsums[i] = tmp[i] - v;  // exclusive
}

// ---------------------------------------------------------------------------
// Phase A2: LDS-sorted scatter. Pass 1 reads dst once (cached in LDS) +
// histogram; pass 2 reads only src from global; pass 3 streams out in
// bucket-grouped dense order. Offsets = deterministic scanned bcount.
// LDS ~76 KB -> 2 blocks/CU (152 KB of 160).
// ---------------------------------------------------------------------------
__global__ void __launch_bounds__(1024, 8)
scatter_sort_kernel(const int* __restrict__ ei32,
                    const long long* __restrict__ ei64,
                    const int* __restrict__ bcount,
                    const int* __restrict__ bsums,
                    unsigned int* __restrict__ packed) {
    __shared__ unsigned int vals[EPB];        // 25.0 KB bucket-grouped words
    __shared__ unsigned int dstin[EPB];       // 25.0 KB cached dst per slot
    __shared__ unsigned short bjs[EPB];       // 12.5 KB bucket id per slot
    __shared__ int hist[NBKT];
    __shared__ int curs[NBKT];
    __shared__ int gbase[NBKT];
    __shared__ int tmp[1024];
    __shared__ int dflag;

    int tid = threadIdx.x;
    if (tid == 0) dflag = 0;
    for (int i = tid; i < NBKT; i += 1024) hist[i] = 0;
    __syncthreads();
    if (tid < 512 && ((const unsigned int*)ei32)[2 * tid + 1] != 0u)
        atomicOr(&dflag, 1);
    __syncthreads();
    bool i64 = (dflag == 0);
    long base = (long)blockIdx.x * EPB;

    // pass 1: read dst once -> LDS cache + per-bucket histogram
    for (int k = tid; k < EPB; k += 1024) {
        long e = base + k;
        int dst = i64 ? (int)ei64[N_EDGES + e] : ei32[N_EDGES + e];
        dstin[k] = (unsigned int)dst;
        atomicAdd(&hist[dst >> 7], 1);
    }
    __syncthreads();

    // 1024-wide exclusive scan (entries >= NBKT padded 0)
    int v = (tid < NBKT) ? hist[tid] : 0;
    tmp[tid] = v;
    __syncthreads();
#pragma unroll
    for (int d = 1; d < 1024; d <<= 1) {
        int t = (tid >= d) ? tmp[tid - d] : 0;
        __syncthreads();
        tmp[tid] += t;
        __syncthreads();
    }
    if (tid < NBKT) {
        int s = tmp[tid] - v;                 // local start
        long gi = (long)tid * EB + blockIdx.x;
        curs[tid] = s;
        gbase[tid] = bcount[gi] + bsums[gi >> 9] - s;
    }
    __syncthreads();

    // pass 2: src from global (first touch), dst from LDS; cursor-scatter
    for (int k = tid; k < EPB; k += 1024) {
        long e = base + k;
        int src = i64 ? (int)ei64[e] : ei32[e];
        unsigned int dst = dstin[k];
        int b = (int)(dst >> 7);
        int p = atomicAdd(&curs[b], 1);
        vals[p] = ((dst & 127u) << 17) | (unsigned int)src;
        bjs[p] = (unsigned short)b;
    }
    __threadfence_block();
    __syncthreads();

    // pass 3: dense-chunk copy to global
    for (int j = tid; j < EPB; j += 1024)
        packed[gbase[bjs[j]] + j] = vals[j];
}

// ---------------------------------------------------------------------------
// Phase B (fused): per-bucket counting sort in LDS + register gather from
// the LDS-sorted list — no global write-back, no meta arrays.
// 1024 threads = 128 nodes x 8 lanes; ~47 KB LDS -> 2 blocks/CU.
// Non-fast buckets (m > SORT_CAP, >=16 sigma, never occurs) leave packed
// untouched and filter-scan it from global.
// ---------------------------------------------------------------------------
__global__ void __launch_bounds__(1024, 2)
sort_gather_kernel(const unsigned int* __restrict__ packed,
                   const int* __restrict__ bcount,
                   const int* __restrict__ bsums,
                   const __half2* __restrict__ h2,
                   const float* __restrict__ b1,
                   const float* __restrict__ W2,
                   const float* __restrict__ b2,
                   float* __restrict__ out) {
    __shared__ unsigned int raw[SORT_CAP];     // 20 KB staged input
    __shared__ unsigned int sortedv[SORT_CAP]; // 20 KB node-grouped srcs
    __shared__ int hist[128];
    __shared__ int starts[128];
    __shared__ int curs[128];
    __shared__ int tmp[1024];

    int b = blockIdx.x;
    int tid = threadIdx.x;
    long gi = (long)b * EB;
    int start = bcount[gi] + bsums[gi >> 9];
    int end;
    if (b + 1 < NBKT) {
        long gj = (long)(b + 1) * EB;
        end = bcount[gj] + bsums[gj >> 9];
    } else {
        end = N_EDGES;
    }
    int m = end - start;
    bool fast = (m <= SORT_CAP);   // uniform across the block

    if (tid < 128) hist[tid] = 0;
    __syncthreads();

    if (fast) {
        // 0. stage raw words (single global read of this bucket)
        for (int k = tid; k < m; k += 1024) raw[k] = packed[start + k];
        __syncthreads();
        // 1. per-node histogram from LDS
        for (int k = tid; k < m; k += 1024)
            atomicAdd(&hist[(int)(raw[k] >> 17)], 1);
    } else {
        for (int k = tid; k < m; k += 1024)
            atomicAdd(&hist[(int)(packed[start + k] >> 17)], 1);
    }
    __syncthreads();

    // 2. exclusive scan of the 128 node counts (entries >= 128 padded 0;
    //    d < 128 suffices: indices < 128 only read lower indices)
    int v = (tid < 128) ? hist[tid] : 0;
    tmp[tid] = v;
    __syncthreads();
#pragma unroll
    for (int d = 1; d < 128; d <<= 1) {
        int t = (tid >= d) ? tmp[tid - d] : 0;
        __syncthreads();
        tmp[tid] += t;
        __syncthreads();
    }
    if (tid < 128) {
        int s = tmp[tid] - v;
        starts[tid] = s;
        curs[tid] = s;
    }
    __syncthreads();

    if (fast) {
        // 3. cursor-scatter src into sortedv[] (LDS -> LDS)
        for (int k = tid; k < m; k += 1024) {
            unsigned int w = raw[k];
            int l = (int)(w >> 17);
            int p = atomicAdd(&curs[l], 1);
            sortedv[p] = w & 0x1FFFFu;
        }
        __threadfence_block();
    }
    __syncthreads();

    // 4. register gather straight from LDS: 128 nodes x 8 lanes
    int l = tid >> 3;              // node-in-bucket 0..127
    int c = tid & 7;               // channel pair 0..7
    int g = b * 128 + l;
    if (g >= N_NODES) return;      // no barriers below

    int deg = hist[l];
    float2 acc0 = {0.0f, 0.0f}, acc1 = {0.0f, 0.0f};

    if (fast) {
        int p = starts[l], pend = p + deg;
        for (; p + 3 < pend; p += 4) {
            int sA = (int)sortedv[p];
            int sB = (int)sortedv[p + 1];
            int sC = (int)sortedv[p + 2];
            int sD = (int)sortedv[p + 3];
            float2 fA = __half22float2(h2[(long)sA * 8 + c]);
            float2 fB = __half22float2(h2[(long)sB * 8 + c]);
            float2 fC = __half22float2(h2[(long)sC * 8 + c]);
            float2 fD = __half22float2(h2[(long)sD * 8 + c]);
            acc0.x += fA.x + fC.x; acc0.y += fA.y + fC.y;
            acc1.x += fB.x + fD.x; acc1.y += fB.y + fD.y;
        }
        for (; p < pend; ++p) {
            float2 f = __half22float2(h2[(long)sortedv[p] * 8 + c]);
            acc0.x += f.x; acc0.y += f.y;
        }
    } else {
        // never-expected universal fallback: filter-scan global packed
        for (int p = start; p < end; ++p) {
            unsigned int w = packed[p];
            if ((int)(w >> 17) == l) {
                float2 f = __half22float2(h2[(long)(w & 0x1FFFFu) * 8 + c]);
                acc0.x += f.x; acc0.y += f.y;
            }
        }
    }

    float inv = 1.0f / fmaxf((float)deg, 1.0f);
    float sx = acc0.x + acc1.x, sy = acc0.y + acc1.y;
    float vv = fmaxf(sx * inv + b1[2 * c], 0.0f)     * W2[2 * c]
             + fmaxf(sy * inv + b1[2 * c + 1], 0.0f) * W2[2 * c + 1];
    vv += __shfl_xor(vv, 1);
    vv += __shfl_xor(vv, 2);
    vv += __shfl_xor(vv, 4);
    if (c == 0) out[g] = vv + b2[0];
}

// ---------------------------------------------------------------------------
// Fallback path (R0): atomic value scatter + finalize. Used if ws too small.
// ---------------------------------------------------------------------------
__global__ void detect_i64_kernel(const unsigned int* __restrict__ ei,
                                  unsigned int* __restrict__ flag) {
    unsigned int v = 0;
    int lane = threadIdx.x;  // 64 threads
    for (int j = lane; j < 512; j += 64) v |= ei[2 * j + 1];
    unsigned long long any_nonzero = __ballot(v != 0u);
    if (lane == 0) *flag = (any_nonzero == 0ULL) ? 1u : 0u;
}

__global__ void linear1_f32_kernel(const float* __restrict__ x,
                                   const float* __restrict__ W1,
                                   float* __restrict__ h, int n) {
    __shared__ float w[16 * 58];
    for (int idx = threadIdx.x; idx < 16 * 58; idx += blockDim.x)
        w[idx] = W1[idx];
    __syncthreads();
    int i = blockIdx.x * blockDim.x + threadIdx.x;
    if (i >= n) return;
    float xv[58];
    const float* xr = x + (long)i * 58;
#pragma unroll
    for (int k = 0; k < 58; ++k) xv[k] = xr[k];
#pragma unroll
    for (int cq = 0; cq < 4; ++cq) {
        float a[4];
#pragma unroll
        for (int r = 0; r < 4; ++r) {
            int ch = cq * 4 + r;
            float acc = 0.0f;
#pragma unroll
            for (int k = 0; k < 58; ++k) acc += xv[k] * w[ch * 58 + k];
            a[r] = acc;
        }
        ((float4*)(h + (long)i * 16))[cq] = make_float4(a[0], a[1], a[2], a[3]);
    }
}

__global__ void scatter_kernel(const int* __restrict__ ei32,
                               const long long* __restrict__ ei64,
                               const unsigned int* __restrict__ flag,
                               const float* __restrict__ h,
                               float* __restrict__ summed,
                               float* __restrict__ cnt) {
    long e = (long)blockIdx.x * blockDim.x + threadIdx.x;
    if (e >= N_EDGES) return;
    long src, dst;
    if (*flag) { src = (long)ei64[e]; dst = (long)ei64[N_EDGES + e]; }
    else       { src = (long)ei32[e]; dst = (long)ei32[N_EDGES + e]; }
    const float4* hs = (const float4*)(h + src * 16);
    float4 a = hs[0], b = hs[1], c = hs[2], d = hs[3];
    float* o = summed + dst * 16;
    atomicAdd(o + 0,  a.x); atomicAdd(o + 1,  a.y);
    atomicAdd(o + 2,  a.z); atomicAdd(o + 3,  a.w);
    atomicAdd(o + 4,  b.x); atomicAdd(o + 5,  b.y);
    atomicAdd(o + 6,  b.z); atomicAdd(o + 7,  b.w);
    atomicAdd(o + 8,  c.x); atomicAdd(o + 9,  c.y);
    atomicAdd(o + 10, c.z); atomicAdd(o + 11, c.w);
    atomicAdd(o + 12, d.x); atomicAdd(o + 13, d.y);
    atomicAdd(o + 14, d.z); atomicAdd(o + 15, d.w);
    atomicAdd(cnt + dst, 1.0f);
}

__global__ void finalize_kernel(const float* __restrict__ summed,
                                const float* __restrict__ cnt,
                                const float* __restrict__ b1,
                                const float* __restrict__ W2,
                                const float* __restrict__ b2,
                                float* __restrict__ out, int n) {
    int i = blockIdx.x * blockDim.x + threadIdx.x;
    if (i >= n) return;
    const float4* s = (const float4*)(summed + (long)i * 16);
    float4 s0 = s[0], s1 = s[1], s2 = s[2], s3 = s[3];
    float sv[16] = {s0.x, s0.y, s0.z, s0.w, s1.x, s1.y, s1.z, s1.w,
                    s2.x, s2.y, s2.z, s2.w, s3.x, s3.y, s3.z, s3.w};
    float inv = 1.0f / fmaxf(cnt[i], 1.0f);
    float acc = b2[0];
#pragma unroll
    for (int c = 0; c < 16; ++c)
        acc += W2[c] * fmaxf(sv[c] * inv + b1[c], 0.0f);
    out[i] = acc;
}

extern "C" void kernel_launch(void* const* d_in, const int* in_sizes, int n_in,
                              void* d_out, int out_size, void* d_ws, size_t ws_size,
                              hipStream_t stream) {
    const float* x  = (const float*)d_in[0];
    const void*  ei = d_in[1];
    const float* W1 = (const float*)d_in[2];
    const float* b1 = (const float*)d_in[3];
    const float* W2 = (const float*)d_in[4];
    const float* b2 = (const float*)d_in[5];
    float* out = (float*)d_out;

    float* ws = (float*)d_ws;

    // Bucket-path workspace (4B words):
    //   h2     :   800,000  (fp16 h, __half2[N][8] = 3.2 MB)
    //   packed : 3,200,000  u32 (bucket-grouped edge words)
    //   bcount :   NSCAN    i32 (400,384; block-local prefix after scan1)
    //   bsums  :     1,024  i32 (scan2 base offsets)
    const size_t need_bkt =
        (size_t)(800000 + 3200000 + NSCAN + 1024) * 4;

    if (ws_size >= need_bkt) {
        __half2*      h2     = (__half2*)ws;
        unsigned int* packed = (unsigned int*)(ws + 800000);
        int*          bcount = (int*)(ws + 800000 + 3200000);
        int*          bsums  = bcount + NSCAN;

        lin_hist_kernel<<<LIN_BLOCKS + EB, 512, 0, stream>>>(
            x, W1, h2, (const int*)ei, (const long long*)ei, bcount);

        scan1_kernel<<<NB_SCAN, SCAN_BLOCK, 0, stream>>>(bcount, bsums, NSCAN);
        scan2_kernel<<<1, 1024, 0, stream>>>(bsums, NB_SCAN);

        scatter_sort_kernel<<<EB, 1024, 0, stream>>>(
            (const int*)ei, (const long long*)ei, bcount, bsums, packed);

        sort_gather_kernel<<<NBKT, 1024, 0, stream>>>(
            packed, bcount, bsums, h2, b1, W2, b2, out);
    } else {
        // Fallback: R0 atomic-scatter path (13.2 MB workspace).
        float* h      = ws;                  // N_NODES * 16
        float* summed = ws + N_NODES * 16;   // N_NODES * 16
        float* cnt    = ws + N_NODES * 32;   // N_NODES
        unsigned int* flag = (unsigned int*)(ws + N_NODES * 33);

        hipMemsetAsync(summed, 0, (size_t)(N_NODES * 17) * sizeof(float), stream);
        detect_i64_kernel<<<1, 64, 0, stream>>>((const unsigned int*)ei, flag);
        linear1_f32_kernel<<<(N_NODES + 127) / 128, 128, 0, stream>>>(x, W1, h, N_NODES);
        scatter_kernel<<<(N_EDGES + 255) / 256, 256, 0, stream>>>(
            (const int*)ei, (const long long*)ei, flag, h, summed, cnt);
        finalize_kernel<<<(N_NODES + 255) / 256, 256, 0, stream>>>(
            summed, cnt, b1, W2, b2, out, N_NODES);
    }
}

// Round 15
// 73.337 us; speedup vs baseline: 1.6251x; 1.0582x over previous
//
#include <hip/hip_runtime.h>
#include <hip/hip_fp16.h>

#define N_NODES 100000
#define N_EDGES 3200000
#define NBKT 782            // buckets of 128 nodes (dst >> 7)
#define EB 512              // phase-A blocks; EB == 2^9 so bsums idx == bucket
#define EPB (N_EDGES / EB)  // 6250 edges per phase-A block
#define SCAN_BLOCK 512
#define NSCAN (NBKT * EB)   // 400384 (bucket-major counts)
#define NB_SCAN ((NSCAN + SCAN_BLOCK - 1) / SCAN_BLOCK)  // 782 == NBKT
#define SORT_CAP 5120       // per-bucket sorted-edge LDS capacity (20 KB)
#define LIN_BLOCKS ((N_NODES + 511) / 512)  // 196 linear-path blocks

// ---------------------------------------------------------------------------
// Wave64-shfl block exclusive scan: 3 barriers instead of ~20 (Hillis-Steele).
// All NT threads must call; entries beyond the logical n must pass v=0.
// ---------------------------------------------------------------------------
template <int NT>
__device__ __forceinline__ int block_excl_scan(int v, int tid, int* wsum) {
    __syncthreads();                    // protects wsum reuse across calls
    int lane = tid & 63;
    int w = tid >> 6;
    int incl = v;
#pragma unroll
    for (int d = 1; d < 64; d <<= 1) {
        int t = __shfl_up(incl, d, 64);
        if (lane >= d) incl += t;
    }
    if (lane == 63) wsum[w] = incl;
    __syncthreads();
    if (w == 0) {
        constexpr int NW = NT / 64;
        int s = (lane < NW) ? wsum[lane] : 0;
        int si = s;
#pragma unroll
        for (int d = 1; d < NW; d <<= 1) {
            int t = __shfl_up(si, d, 64);
            if (lane >= d) si += t;
        }
        if (lane < NW) wsum[lane] = si - s;   // exclusive wave base
    }
    __syncthreads();
    return incl - v + wsum[w];
}

// ---------------------------------------------------------------------------
// Fused phase A0+A1: blocks [0, LIN_BLOCKS) compute h2 = fp16(x @ W1^T);
// blocks [LIN_BLOCKS, LIN_BLOCKS+EB) histogram dst buckets (LDS atomics,
// deterministic bucket-major bcount writes). Both paths block-uniform.
// ---------------------------------------------------------------------------
__global__ void lin_hist_kernel(const float* __restrict__ x,
                                const float* __restrict__ W1,
                                __half2* __restrict__ h2,
                                const int* __restrict__ ei32,
                                const long long* __restrict__ ei64,
                                int* __restrict__ bcount) {
    __shared__ float w[16 * 58];
    __shared__ int hist[NBKT];
    __shared__ int dflag;
    int tid = threadIdx.x;

    if (blockIdx.x < LIN_BLOCKS) {
        // ---- linear1 path ----
        for (int idx = tid; idx < 16 * 58; idx += 512) w[idx] = W1[idx];
        __syncthreads();

        int i = blockIdx.x * 512 + tid;
        if (i >= N_NODES) return;

        float xv[58];
        const float* xr = x + (long)i * 58;
#pragma unroll
        for (int k = 0; k < 58; ++k) xv[k] = xr[k];

        __half2 o[8];
#pragma unroll
        for (int q = 0; q < 8; ++q) {
            float a[2];
#pragma unroll
            for (int r = 0; r < 2; ++r) {
                int c = q * 2 + r;
                float acc = 0.0f;
#pragma unroll
                for (int k = 0; k < 58; ++k) acc += xv[k] * w[c * 58 + k];
                a[r] = acc;
            }
            o[q] = __floats2half2_rn(a[0], a[1]);
        }
        float4* dst = (float4*)(h2 + (long)i * 8);
        float4* src = (float4*)o;
        dst[0] = src[0];
        dst[1] = src[1];
    } else {
        // ---- hist path ----
        int blk = blockIdx.x - LIN_BLOCKS;
        if (tid == 0) dflag = 0;
        for (int i = tid; i < NBKT; i += 512) hist[i] = 0;
        __syncthreads();
        if (((const unsigned int*)ei32)[2 * tid + 1] != 0u) atomicOr(&dflag, 1);
        __syncthreads();
        bool i64 = (dflag == 0);

        long base = (long)blk * EPB;
        for (int k = tid; k < EPB; k += 512) {
            long e = base + k;
            int dst = i64 ? (int)ei64[N_EDGES + e] : ei32[N_EDGES + e];
            atomicAdd(&hist[dst >> 7], 1);
        }
        __syncthreads();
        for (int b = tid; b < NBKT; b += 512)
            bcount[(long)b * EB + blk] = hist[b];
    }
}

// ---------------------------------------------------------------------------
// scan1: block-local exclusive scan of bcount in place + raw block totals.
// Block b handles bucket b's 512 per-block counts; bsums[b] = bucket total.
// Consumers scan bsums themselves (no scan2 kernel).
// ---------------------------------------------------------------------------
__global__ void __launch_bounds__(SCAN_BLOCK)
scan1_kernel(int* __restrict__ data, int* __restrict__ bsums, int n) {
    __shared__ int wsum[16];
    int i = blockIdx.x * SCAN_BLOCK + threadIdx.x;
    int v = (i < n) ? data[i] : 0;
    int excl = block_excl_scan<SCAN_BLOCK>(v, threadIdx.x, wsum);
    if (i < n) data[i] = excl;
    if (threadIdx.x == SCAN_BLOCK - 1) bsums[blockIdx.x] = excl + v;
}

// ---------------------------------------------------------------------------
// Phase A2: LDS-sorted scatter. Pass 1 reads dst once (cached in LDS) +
// histogram; in-LDS shfl-scans of local hist AND global bsums (782 raw
// totals) give deterministic global offsets; pass 2 reads only src; pass 3
// streams bucket-grouped dense chunks to global. ~72 KB LDS -> 2 blocks/CU.
// ---------------------------------------------------------------------------
__global__ void __launch_bounds__(1024, 8)
scatter_sort_kernel(const int* __restrict__ ei32,
                    const long long* __restrict__ ei64,
                    const int* __restrict__ bcount,
                    const int* __restrict__ bsums,
                    unsigned int* __restrict__ packed) {
    __shared__ unsigned int vals[EPB];        // 25.0 KB bucket-grouped words
    __shared__ unsigned int dstin[EPB];       // 25.0 KB cached dst per slot
    __shared__ unsigned short bjs[EPB];       // 12.5 KB bucket id per slot
    __shared__ int hist[NBKT];
    __shared__ int curs[NBKT];
    __shared__ int gbase[NBKT];
    __shared__ int wsum[16];
    __shared__ int dflag;

    int tid = threadIdx.x;
    if (tid == 0) dflag = 0;
    for (int i = tid; i < NBKT; i += 1024) hist[i] = 0;
    __syncthreads();
    if (tid < 512 && ((const unsigned int*)ei32)[2 * tid + 1] != 0u)
        atomicOr(&dflag, 1);
    __syncthreads();
    bool i64 = (dflag == 0);
    long base = (long)blockIdx.x * EPB;

    // pass 1: read dst once -> LDS cache + per-bucket histogram
    for (int k = tid; k < EPB; k += 1024) {
        long e = base + k;
        int dst = i64 ? (int)ei64[N_EDGES + e] : ei32[N_EDGES + e];
        dstin[k] = (unsigned int)dst;
        atomicAdd(&hist[dst >> 7], 1);
    }
    __syncthreads();

    // local hist scan + bsums scan (3 barriers each, shfl-based)
    int hv = (tid < NBKT) ? hist[tid] : 0;
    int lexcl = block_excl_scan<1024>(hv, tid, wsum);
    int bv = (tid < NBKT) ? bsums[tid] : 0;
    int sb = block_excl_scan<1024>(bv, tid, wsum);
    if (tid < NBKT) {
        // gi = tid*EB + blockIdx.x; gi>>9 == tid since EB == 512
        long gi = (long)tid * EB + blockIdx.x;
        curs[tid] = lexcl;
        gbase[tid] = bcount[gi] + sb - lexcl;
    }
    __syncthreads();

    // pass 2: src from global (first touch), dst from LDS; cursor-scatter
    for (int k = tid; k < EPB; k += 1024) {
        long e = base + k;
        int src = i64 ? (int)ei64[e] : ei32[e];
        unsigned int dst = dstin[k];
        int b = (int)(dst >> 7);
        int p = atomicAdd(&curs[b], 1);
        vals[p] = ((dst & 127u) << 17) | (unsigned int)src;
        bjs[p] = (unsigned short)b;
    }
    __threadfence_block();
    __syncthreads();

    // pass 3: dense-chunk copy to global
    for (int j = tid; j < EPB; j += 1024)
        packed[gbase[bjs[j]] + j] = vals[j];
}

// ---------------------------------------------------------------------------
// Phase B (fused): per-bucket counting sort in LDS + register gather from
// the LDS-sorted list. Bucket bounds come from an in-LDS scan of bsums
// (raw totals): start = sb[b], end = sb[b] + bsums[b] — no bcount needed.
// 1024 threads = 128 nodes x 8 lanes; ~42 KB LDS -> 2 blocks/CU.
// ---------------------------------------------------------------------------
__global__ void __launch_bounds__(1024, 2)
sort_gather_kernel(const unsigned int* __restrict__ packed,
                   const int* __restrict__ bsums,
                   const __half2* __restrict__ h2,
                   const float* __restrict__ b1,
                   const float* __restrict__ W2,
                   const float* __restrict__ b2,
                   float* __restrict__ out) {
    __shared__ unsigned int raw[SORT_CAP];     // 20 KB staged input
    __shared__ unsigned int sortedv[SORT_CAP]; // 20 KB node-grouped srcs
    __shared__ int hist[128];
    __shared__ int starts[128];
    __shared__ int curs[128];
    __shared__ int wsum[16];
    __shared__ int bounds[2];

    int b = blockIdx.x;
    int tid = threadIdx.x;

    if (tid < 128) hist[tid] = 0;

    // bucket bounds via in-LDS scan of the 782 raw totals
    int bv = (tid < NBKT) ? bsums[tid] : 0;
    int sb = block_excl_scan<1024>(bv, tid, wsum);
    if (tid == b) { bounds[0] = sb; bounds[1] = sb + bv; }  // b < NBKT < 1024
    __syncthreads();

    int start = bounds[0];
    int end = bounds[1];
    int m = end - start;
    bool fast = (m <= SORT_CAP);   // uniform across the block

    if (fast) {
        // 0. stage raw words (single global read of this bucket)
        for (int k = tid; k < m; k += 1024) raw[k] = packed[start + k];
        __syncthreads();
        // 1. per-node histogram from LDS
        for (int k = tid; k < m; k += 1024)
            atomicAdd(&hist[(int)(raw[k] >> 17)], 1);
    } else {
        for (int k = tid; k < m; k += 1024)
            atomicAdd(&hist[(int)(packed[start + k] >> 17)], 1);
    }
    __syncthreads();

    // 2. exclusive scan of the 128 node counts (shfl-based)
    int hv = (tid < 128) ? hist[tid] : 0;
    int nexcl = block_excl_scan<1024>(hv, tid, wsum);
    if (tid < 128) {
        starts[tid] = nexcl;
        curs[tid] = nexcl;
    }
    __syncthreads();

    if (fast) {
        // 3. cursor-scatter src into sortedv[] (LDS -> LDS)
        for (int k = tid; k < m; k += 1024) {
            unsigned int w = raw[k];
            int l = (int)(w >> 17);
            int p = atomicAdd(&curs[l], 1);
            sortedv[p] = w & 0x1FFFFu;
        }
        __threadfence_block();
    }
    __syncthreads();

    // 4. register gather straight from LDS: 128 nodes x 8 lanes
    int l = tid >> 3;              // node-in-bucket 0..127
    int c = tid & 7;               // channel pair 0..7
    int g = b * 128 + l;
    if (g >= N_NODES) return;      // no barriers below

    int deg = hist[l];
    float2 acc0 = {0.0f, 0.0f}, acc1 = {0.0f, 0.0f};

    if (fast) {
        int p = starts[l], pend = p + deg;
        for (; p + 3 < pend; p += 4) {
            int sA = (int)sortedv[p];
            int sB = (int)sortedv[p + 1];
            int sC = (int)sortedv[p + 2];
            int sD = (int)sortedv[p + 3];
            float2 fA = __half22float2(h2[(long)sA * 8 + c]);
            float2 fB = __half22float2(h2[(long)sB * 8 + c]);
            float2 fC = __half22float2(h2[(long)sC * 8 + c]);
            float2 fD = __half22float2(h2[(long)sD * 8 + c]);
            acc0.x += fA.x + fC.x; acc0.y += fA.y + fC.y;
            acc1.x += fB.x + fD.x; acc1.y += fB.y + fD.y;
        }
        for (; p < pend; ++p) {
            float2 f = __half22float2(h2[(long)sortedv[p] * 8 + c]);
            acc0.x += f.x; acc0.y += f.y;
        }
    } else {
        // never-expected universal fallback: filter-scan global packed
        for (int p = start; p < end; ++p) {
            unsigned int w = packed[p];
            if ((int)(w >> 17) == l) {
                float2 f = __half22float2(h2[(long)(w & 0x1FFFFu) * 8 + c]);
                acc0.x += f.x; acc0.y += f.y;
            }
        }
    }

    float inv = 1.0f / fmaxf((float)deg, 1.0f);
    float sx = acc0.x + acc1.x, sy = acc0.y + acc1.y;
    float vv = fmaxf(sx * inv + b1[2 * c], 0.0f)     * W2[2 * c]
             + fmaxf(sy * inv + b1[2 * c + 1], 0.0f) * W2[2 * c + 1];
    vv += __shfl_xor(vv, 1);
    vv += __shfl_xor(vv, 2);
    vv += __shfl_xor(vv, 4);
    if (c == 0) out[g] = vv + b2[0];
}

// ---------------------------------------------------------------------------
// Fallback path (R0): atomic value scatter + finalize. Used if ws too small.
// ---------------------------------------------------------------------------
__global__ void detect_i64_kernel(const unsigned int* __restrict__ ei,
                                  unsigned int* __restrict__ flag) {
    unsigned int v = 0;
    int lane = threadIdx.x;  // 64 threads
    for (int j = lane; j < 512; j += 64) v |= ei[2 * j + 1];
    unsigned long long any_nonzero = __ballot(v != 0u);
    if (lane == 0) *flag = (any_nonzero == 0ULL) ? 1u : 0u;
}

__global__ void linear1_f32_kernel(const float* __restrict__ x,
                                   const float* __restrict__ W1,
                                   float* __restrict__ h, int n) {
    __shared__ float w[16 * 58];
    for (int idx = threadIdx.x; idx < 16 * 58; idx += blockDim.x)
        w[idx] = W1[idx];
    __syncthreads();
    int i = blockIdx.x * blockDim.x + threadIdx.x;
    if (i >= n) return;
    float xv[58];
    const float* xr = x + (long)i * 58;
#pragma unroll
    for (int k = 0; k < 58; ++k) xv[k] = xr[k];
#pragma unroll
    for (int cq = 0; cq < 4; ++cq) {
        float a[4];
#pragma unroll
        for (int r = 0; r < 4; ++r) {
            int ch = cq * 4 + r;
            float acc = 0.0f;
#pragma unroll
            for (int k = 0; k < 58; ++k) acc += xv[k] * w[ch * 58 + k];
            a[r] = acc;
        }
        ((float4*)(h + (long)i * 16))[cq] = make_float4(a[0], a[1], a[2], a[3]);
    }
}

__global__ void scatter_kernel(const int* __restrict__ ei32,
                               const long long* __restrict__ ei64,
                               const unsigned int* __restrict__ flag,
                               const float* __restrict__ h,
                               float* __restrict__ summed,
                               float* __restrict__ cnt) {
    long e = (long)blockIdx.x * blockDim.x + threadIdx.x;
    if (e >= N_EDGES) return;
    long src, dst;
    if (*flag) { src = (long)ei64[e]; dst = (long)ei64[N_EDGES + e]; }
    else       { src = (long)ei32[e]; dst = (long)ei32[N_EDGES + e]; }
    const float4* hs = (const float4*)(h + src * 16);
    float4 a = hs[0], b = hs[1], c = hs[2], d = hs[3];
    float* o = summed + dst * 16;
    atomicAdd(o + 0,  a.x); atomicAdd(o + 1,  a.y);
    atomicAdd(o + 2,  a.z); atomicAdd(o + 3,  a.w);
    atomicAdd(o + 4,  b.x); atomicAdd(o + 5,  b.y);
    atomicAdd(o + 6,  b.z); atomicAdd(o + 7,  b.w);
    atomicAdd(o + 8,  c.x); atomicAdd(o + 9,  c.y);
    atomicAdd(o + 10, c.z); atomicAdd(o + 11, c.w);
    atomicAdd(o + 12, d.x); atomicAdd(o + 13, d.y);
    atomicAdd(o + 14, d.z); atomicAdd(o + 15, d.w);
    atomicAdd(cnt + dst, 1.0f);
}

__global__ void finalize_kernel(const float* __restrict__ summed,
                                const float* __restrict__ cnt,
                                const float* __restrict__ b1,
                                const float* __restrict__ W2,
                                const float* __restrict__ b2,
                                float* __restrict__ out, int n) {
    int i = blockIdx.x * blockDim.x + threadIdx.x;
    if (i >= n) return;
    const float4* s = (const float4*)(summed + (long)i * 16);
    float4 s0 = s[0], s1 = s[1], s2 = s[2], s3 = s[3];
    float sv[16] = {s0.x, s0.y, s0.z, s0.w, s1.x, s1.y, s1.z, s1.w,
                    s2.x, s2.y, s2.z, s2.w, s3.x, s3.y, s3.z, s3.w};
    float inv = 1.0f / fmaxf(cnt[i], 1.0f);
    float acc = b2[0];
#pragma unroll
    for (int c = 0; c < 16; ++c)
        acc += W2[c] * fmaxf(sv[c] * inv + b1[c], 0.0f);
    out[i] = acc;
}

extern "C" void kernel_launch(void* const* d_in, const int* in_sizes, int n_in,
                              void* d_out, int out_size, void* d_ws, size_t ws_size,
                              hipStream_t stream) {
    const float* x  = (const float*)d_in[0];
    const void*  ei = d_in[1];
    const float* W1 = (const float*)d_in[2];
    const float* b1 = (const float*)d_in[3];
    const float* W2 = (const float*)d_in[4];
    const float* b2 = (const float*)d_in[5];
    float* out = (float*)d_out;

    float* ws = (float*)d_ws;

    // Bucket-path workspace (4B words):
    //   h2     :   800,000  (fp16 h, __half2[N][8] = 3.2 MB)
    //   packed : 3,200,000  u32 (bucket-grouped edge words)
    //   bcount :   NSCAN    i32 (400,384; block-local prefix after scan1)
    //   bsums  :     1,024  i32 (raw per-bucket totals; consumers scan)
    const size_t need_bkt =
        (size_t)(800000 + 3200000 + NSCAN + 1024) * 4;

    if (ws_size >= need_bkt) {
        __half2*      h2     = (__half2*)ws;
        unsigned int* packed = (unsigned int*)(ws + 800000);
        int*          bcount = (int*)(ws + 800000 + 3200000);
        int*          bsums  = bcount + NSCAN;

        lin_hist_kernel<<<LIN_BLOCKS + EB, 512, 0, stream>>>(
            x, W1, h2, (const int*)ei, (const long long*)ei, bcount);

        scan1_kernel<<<NB_SCAN, SCAN_BLOCK, 0, stream>>>(bcount, bsums, NSCAN);

        scatter_sort_kernel<<<EB, 1024, 0, stream>>>(
            (const int*)ei, (const long long*)ei, bcount, bsums, packed);

        sort_gather_kernel<<<NBKT, 1024, 0, stream>>>(
            packed, bsums, h2, b1, W2, b2, out);
    } else {
        // Fallback: R0 atomic-scatter path (13.2 MB workspace).
        float* h      = ws;                  // N_NODES * 16
        float* summed = ws + N_NODES * 16;   // N_NODES * 16
        float* cnt    = ws + N_NODES * 32;   // N_NODES
        unsigned int* flag = (unsigned int*)(ws + N_NODES * 33);

        hipMemsetAsync(summed, 0, (size_t)(N_NODES * 17) * sizeof(float), stream);
        detect_i64_kernel<<<1, 64, 0, stream>>>((const unsigned int*)ei, flag);
        linear1_f32_kernel<<<(N_NODES + 127) / 128, 128, 0, stream>>>(x, W1, h, N_NODES);
        scatter_kernel<<<(N_EDGES + 255) / 256, 256, 0, stream>>>(
            (const int*)ei, (const long long*)ei, flag, h, summed, cnt);
        finalize_kernel<<<(N_NODES + 255) / 256, 256, 0, stream>>>(
            summed, cnt, b1, W2, b2, out, N_NODES);
    }
}

// Round 16
// 71.502 us; speedup vs baseline: 1.6669x; 1.0257x over previous
//
#include <hip/hip_runtime.h>
#include <hip/hip_fp16.h>

#define N_NODES 100000
#define N_EDGES 3200000
#define NBKT 782            // buckets of 128 nodes (dst >> 7)
#define EB 512              // phase-A blocks; EB == 2^9 so bsums idx == bucket
#define EPB (N_EDGES / EB)  // 6250 edges per phase-A block
#define SCAN_BLOCK 512
#define NSCAN (NBKT * EB)   // 400384 (bucket-major counts)
#define NB_SCAN ((NSCAN + SCAN_BLOCK - 1) / SCAN_BLOCK)  // 782 == NBKT
#define SORT_CAP 5120       // per-bucket sorted-edge LDS capacity (20 KB)
#define LIN_BLOCKS ((N_NODES + 511) / 512)  // 196 linear-path blocks

// ---------------------------------------------------------------------------
// Wave64-shfl block exclusive scan (int): 3 barriers.
// All NT threads must call; entries beyond the logical n must pass v=0.
// ---------------------------------------------------------------------------
template <int NT>
__device__ __forceinline__ int block_excl_scan(int v, int tid, int* wsum) {
    __syncthreads();                    // protects wsum reuse across calls
    int lane = tid & 63;
    int w = tid >> 6;
    int incl = v;
#pragma unroll
    for (int d = 1; d < 64; d <<= 1) {
        int t = __shfl_up(incl, d, 64);
        if (lane >= d) incl += t;
    }
    if (lane == 63) wsum[w] = incl;
    __syncthreads();
    if (w == 0) {
        constexpr int NW = NT / 64;
        int s = (lane < NW) ? wsum[lane] : 0;
        int si = s;
#pragma unroll
        for (int d = 1; d < NW; d <<= 1) {
            int t = __shfl_up(si, d, 64);
            if (lane >= d) si += t;
        }
        if (lane < NW) wsum[lane] = si - s;   // exclusive wave base
    }
    __syncthreads();
    return incl - v + wsum[w];
}

// ---------------------------------------------------------------------------
// Dual exclusive scan: two independent non-negative int sequences packed in
// one long long (low/high 32). Each half's total < 2^31 so no cross-carry.
// ---------------------------------------------------------------------------
template <int NT>
__device__ __forceinline__ long long block_excl_scan2(long long v, int tid,
                                                      long long* wsum) {
    __syncthreads();
    int lane = tid & 63;
    int w = tid >> 6;
    long long incl = v;
#pragma unroll
    for (int d = 1; d < 64; d <<= 1) {
        long long t = __shfl_up(incl, d, 64);
        if (lane >= d) incl += t;
    }
    if (lane == 63) wsum[w] = incl;
    __syncthreads();
    if (w == 0) {
        constexpr int NW = NT / 64;
        long long s = (lane < NW) ? wsum[lane] : 0;
        long long si = s;
#pragma unroll
        for (int d = 1; d < NW; d <<= 1) {
            long long t = __shfl_up(si, d, 64);
            if (lane >= d) si += t;
        }
        if (lane < NW) wsum[lane] = si - s;
    }
    __syncthreads();
    return incl - v + wsum[w];
}

// ---------------------------------------------------------------------------
// Fused phase A0+A1: blocks [0, LIN_BLOCKS) compute h2 = fp16(x @ W1^T);
// blocks [LIN_BLOCKS, LIN_BLOCKS+EB) histogram dst buckets (LDS atomics,
// deterministic bucket-major bcount writes). Both paths block-uniform.
// ---------------------------------------------------------------------------
__global__ void lin_hist_kernel(const float* __restrict__ x,
                                const float* __restrict__ W1,
                                __half2* __restrict__ h2,
                                const int* __restrict__ ei32,
                                const long long* __restrict__ ei64,
                                int* __restrict__ bcount) {
    __shared__ float w[16 * 58];
    __shared__ int hist[NBKT];
    __shared__ int dflag;
    int tid = threadIdx.x;

    if (blockIdx.x < LIN_BLOCKS) {
        // ---- linear1 path ----
        for (int idx = tid; idx < 16 * 58; idx += 512) w[idx] = W1[idx];
        __syncthreads();

        int i = blockIdx.x * 512 + tid;
        if (i >= N_NODES) return;

        float xv[58];
        const float* xr = x + (long)i * 58;
#pragma unroll
        for (int k = 0; k < 58; ++k) xv[k] = xr[k];

        __half2 o[8];
#pragma unroll
        for (int q = 0; q < 8; ++q) {
            float a[2];
#pragma unroll
            for (int r = 0; r < 2; ++r) {
                int c = q * 2 + r;
                float acc = 0.0f;
#pragma unroll
                for (int k = 0; k < 58; ++k) acc += xv[k] * w[c * 58 + k];
                a[r] = acc;
            }
            o[q] = __floats2half2_rn(a[0], a[1]);
        }
        float4* dst = (float4*)(h2 + (long)i * 8);
        float4* src = (float4*)o;
        dst[0] = src[0];
        dst[1] = src[1];
    } else {
        // ---- hist path ----
        int blk = blockIdx.x - LIN_BLOCKS;
        if (tid == 0) dflag = 0;
        for (int i = tid; i < NBKT; i += 512) hist[i] = 0;
        __syncthreads();
        if (((const unsigned int*)ei32)[2 * tid + 1] != 0u) atomicOr(&dflag, 1);
        __syncthreads();
        bool i64 = (dflag == 0);

        long base = (long)blk * EPB;
        for (int k = tid; k < EPB; k += 512) {
            long e = base + k;
            int dst = i64 ? (int)ei64[N_EDGES + e] : ei32[N_EDGES + e];
            atomicAdd(&hist[dst >> 7], 1);
        }
        __syncthreads();
        for (int b = tid; b < NBKT; b += 512)
            bcount[(long)b * EB + blk] = hist[b];
    }
}

// ---------------------------------------------------------------------------
// scan1: block-local exclusive scan of bcount in place + raw block totals.
// Block b handles bucket b's 512 per-block counts; bsums[b] = bucket total.
// ---------------------------------------------------------------------------
__global__ void __launch_bounds__(SCAN_BLOCK)
scan1_kernel(int* __restrict__ data, int* __restrict__ bsums, int n) {
    __shared__ int wsum[16];
    int i = blockIdx.x * SCAN_BLOCK + threadIdx.x;
    int v = (i < n) ? data[i] : 0;
    int excl = block_excl_scan<SCAN_BLOCK>(v, threadIdx.x, wsum);
    if (i < n) data[i] = excl;
    if (threadIdx.x == SCAN_BLOCK - 1) bsums[blockIdx.x] = excl + v;
}

// ---------------------------------------------------------------------------
// Phase A2: LDS-sorted scatter. Pass 1 reads dst once (cached in LDS) +
// histogram; ONE dual shfl-scan gives both the local offsets and the
// cross-bucket base (bsums scan); block 0 publishes bstart[] for phase B.
// Pass 2 reads only src; pass 3 streams bucket-grouped dense chunks out.
// ---------------------------------------------------------------------------
__global__ void __launch_bounds__(1024, 8)
scatter_sort_kernel(const int* __restrict__ ei32,
                    const long long* __restrict__ ei64,
                    const int* __restrict__ bcount,
                    const int* __restrict__ bsums,
                    unsigned int* __restrict__ packed,
                    int* __restrict__ bstart) {
    __shared__ unsigned int vals[EPB];        // 25.0 KB bucket-grouped words
    __shared__ unsigned int dstin[EPB];       // 25.0 KB cached dst per slot
    __shared__ unsigned short bjs[EPB];       // 12.5 KB bucket id per slot
    __shared__ int hist[NBKT];
    __shared__ int curs[NBKT];
    __shared__ int gbase[NBKT];
    __shared__ long long wsumll[16];
    __shared__ int dflag;

    int tid = threadIdx.x;
    if (tid == 0) dflag = 0;
    for (int i = tid; i < NBKT; i += 1024) hist[i] = 0;
    __syncthreads();
    if (tid < 512 && ((const unsigned int*)ei32)[2 * tid + 1] != 0u)
        atomicOr(&dflag, 1);
    __syncthreads();
    bool i64 = (dflag == 0);
    long base = (long)blockIdx.x * EPB;

    // pass 1: read dst once -> LDS cache + per-bucket histogram
    for (int k = tid; k < EPB; k += 1024) {
        long e = base + k;
        int dst = i64 ? (int)ei64[N_EDGES + e] : ei32[N_EDGES + e];
        dstin[k] = (unsigned int)dst;
        atomicAdd(&hist[dst >> 7], 1);
    }
    __syncthreads();

    // dual scan: low = local hist (sum <= 6250), high = bsums (sum <= 3.2M)
    int hv = (tid < NBKT) ? hist[tid] : 0;
    int bv = (tid < NBKT) ? bsums[tid] : 0;
    long long pk = ((long long)bv << 32) | (unsigned int)hv;
    long long sc = block_excl_scan2<1024>(pk, tid, wsumll);
    int lexcl = (int)(sc & 0xFFFFFFFFll);
    int sb = (int)(sc >> 32);
    if (tid < NBKT) {
        // gi = tid*EB + blockIdx.x; gi>>9 == tid since EB == 512
        long gi = (long)tid * EB + blockIdx.x;
        curs[tid] = lexcl;
        gbase[tid] = bcount[gi] + sb - lexcl;
    }
    if (blockIdx.x == 0) {
        if (tid < NBKT) bstart[tid] = sb;
        if (tid == 0) bstart[NBKT] = N_EDGES;
    }
    __syncthreads();

    // pass 2: src from global (first touch), dst from LDS; cursor-scatter
    for (int k = tid; k < EPB; k += 1024) {
        long e = base + k;
        int src = i64 ? (int)ei64[e] : ei32[e];
        unsigned int dst = dstin[k];
        int b = (int)(dst >> 7);
        int p = atomicAdd(&curs[b], 1);
        vals[p] = ((dst & 127u) << 17) | (unsigned int)src;
        bjs[p] = (unsigned short)b;
    }
    __threadfence_block();
    __syncthreads();

    // pass 3: dense-chunk copy to global
    for (int j = tid; j < EPB; j += 1024)
        packed[gbase[bjs[j]] + j] = vals[j];
}

// ---------------------------------------------------------------------------
// Phase B (fused): per-bucket counting sort in LDS + register gather from
// the LDS-sorted list. Bucket bounds read directly from bstart[] (published
// by scatter block 0). 1024 threads = 128 nodes x 8 lanes; ~42 KB LDS.
// ---------------------------------------------------------------------------
__global__ void __launch_bounds__(1024, 2)
sort_gather_kernel(const unsigned int* __restrict__ packed,
                   const int* __restrict__ bstart,
                   const __half2* __restrict__ h2,
                   const float* __restrict__ b1,
                   const float* __restrict__ W2,
                   const float* __restrict__ b2,
                   float* __restrict__ out) {
    __shared__ unsigned int raw[SORT_CAP];     // 20 KB staged input
    __shared__ unsigned int sortedv[SORT_CAP]; // 20 KB node-grouped srcs
    __shared__ int hist[128];
    __shared__ int starts[128];
    __shared__ int curs[128];
    __shared__ int wsum[16];

    int b = blockIdx.x;
    int tid = threadIdx.x;
    int start = bstart[b];
    int end = bstart[b + 1];
    int m = end - start;
    bool fast = (m <= SORT_CAP);   // uniform across the block

    if (tid < 128) hist[tid] = 0;
    __syncthreads();

    if (fast) {
        // 0. stage raw words (single global read of this bucket)
        for (int k = tid; k < m; k += 1024) raw[k] = packed[start + k];
        __syncthreads();
        // 1. per-node histogram from LDS
        for (int k = tid; k < m; k += 1024)
            atomicAdd(&hist[(int)(raw[k] >> 17)], 1);
    } else {
        for (int k = tid; k < m; k += 1024)
            atomicAdd(&hist[(int)(packed[start + k] >> 17)], 1);
    }
    __syncthreads();

    // 2. exclusive scan of the 128 node counts (shfl-based)
    int hv = (tid < 128) ? hist[tid] : 0;
    int nexcl = block_excl_scan<1024>(hv, tid, wsum);
    if (tid < 128) {
        starts[tid] = nexcl;
        curs[tid] = nexcl;
    }
    __syncthreads();

    if (fast) {
        // 3. cursor-scatter src into sortedv[] (LDS -> LDS)
        for (int k = tid; k < m; k += 1024) {
            unsigned int w = raw[k];
            int l = (int)(w >> 17);
            int p = atomicAdd(&curs[l], 1);
            sortedv[p] = w & 0x1FFFFu;
        }
        __threadfence_block();
    }
    __syncthreads();

    // 4. register gather straight from LDS: 128 nodes x 8 lanes, unroll-8
    int l = tid >> 3;              // node-in-bucket 0..127
    int c = tid & 7;               // channel pair 0..7
    int g = b * 128 + l;
    if (g >= N_NODES) return;      // no barriers below

    int deg = hist[l];
    float2 acc0 = {0.0f, 0.0f}, acc1 = {0.0f, 0.0f};
    float2 acc2 = {0.0f, 0.0f}, acc3 = {0.0f, 0.0f};

    if (fast) {
        int p = starts[l], pend = p + deg;
        for (; p + 7 < pend; p += 8) {
            int s0 = (int)sortedv[p];
            int s1 = (int)sortedv[p + 1];
            int s2 = (int)sortedv[p + 2];
            int s3 = (int)sortedv[p + 3];
            int s4 = (int)sortedv[p + 4];
            int s5 = (int)sortedv[p + 5];
            int s6 = (int)sortedv[p + 6];
            int s7 = (int)sortedv[p + 7];
            float2 f0 = __half22float2(h2[(long)s0 * 8 + c]);
            float2 f1 = __half22float2(h2[(long)s1 * 8 + c]);
            float2 f2 = __half22float2(h2[(long)s2 * 8 + c]);
            float2 f3 = __half22float2(h2[(long)s3 * 8 + c]);
            float2 f4 = __half22float2(h2[(long)s4 * 8 + c]);
            float2 f5 = __half22float2(h2[(long)s5 * 8 + c]);
            float2 f6 = __half22float2(h2[(long)s6 * 8 + c]);
            float2 f7 = __half22float2(h2[(long)s7 * 8 + c]);
            acc0.x += f0.x + f4.x; acc0.y += f0.y + f4.y;
            acc1.x += f1.x + f5.x; acc1.y += f1.y + f5.y;
            acc2.x += f2.x + f6.x; acc2.y += f2.y + f6.y;
            acc3.x += f3.x + f7.x; acc3.y += f3.y + f7.y;
        }
        for (; p + 1 < pend; p += 2) {
            int sA = (int)sortedv[p];
            int sB = (int)sortedv[p + 1];
            float2 fA = __half22float2(h2[(long)sA * 8 + c]);
            float2 fB = __half22float2(h2[(long)sB * 8 + c]);
            acc0.x += fA.x; acc0.y += fA.y;
            acc1.x += fB.x; acc1.y += fB.y;
        }
        if (p < pend) {
            float2 f = __half22float2(h2[(long)sortedv[p] * 8 + c]);
            acc0.x += f.x; acc0.y += f.y;
        }
    } else {
        // never-expected universal fallback: filter-scan global packed
        for (int p = start; p < end; ++p) {
            unsigned int w = packed[p];
            if ((int)(w >> 17) == l) {
                float2 f = __half22float2(h2[(long)(w & 0x1FFFFu) * 8 + c]);
                acc0.x += f.x; acc0.y += f.y;
            }
        }
    }

    float inv = 1.0f / fmaxf((float)deg, 1.0f);
    float sx = acc0.x + acc1.x + acc2.x + acc3.x;
    float sy = acc0.y + acc1.y + acc2.y + acc3.y;
    float vv = fmaxf(sx * inv + b1[2 * c], 0.0f)     * W2[2 * c]
             + fmaxf(sy * inv + b1[2 * c + 1], 0.0f) * W2[2 * c + 1];
    vv += __shfl_xor(vv, 1);
    vv += __shfl_xor(vv, 2);
    vv += __shfl_xor(vv, 4);
    if (c == 0) out[g] = vv + b2[0];
}

// ---------------------------------------------------------------------------
// Fallback path (R0): atomic value scatter + finalize. Used if ws too small.
// ---------------------------------------------------------------------------
__global__ void detect_i64_kernel(const unsigned int* __restrict__ ei,
                                  unsigned int* __restrict__ flag) {
    unsigned int v = 0;
    int lane = threadIdx.x;  // 64 threads
    for (int j = lane; j < 512; j += 64) v |= ei[2 * j + 1];
    unsigned long long any_nonzero = __ballot(v != 0u);
    if (lane == 0) *flag = (any_nonzero == 0ULL) ? 1u : 0u;
}

__global__ void linear1_f32_kernel(const float* __restrict__ x,
                                   const float* __restrict__ W1,
                                   float* __restrict__ h, int n) {
    __shared__ float w[16 * 58];
    for (int idx = threadIdx.x; idx < 16 * 58; idx += blockDim.x)
        w[idx] = W1[idx];
    __syncthreads();
    int i = blockIdx.x * blockDim.x + threadIdx.x;
    if (i >= n) return;
    float xv[58];
    const float* xr = x + (long)i * 58;
#pragma unroll
    for (int k = 0; k < 58; ++k) xv[k] = xr[k];
#pragma unroll
    for (int cq = 0; cq < 4; ++cq) {
        float a[4];
#pragma unroll
        for (int r = 0; r < 4; ++r) {
            int ch = cq * 4 + r;
            float acc = 0.0f;
#pragma unroll
            for (int k = 0; k < 58; ++k) acc += xv[k] * w[ch * 58 + k];
            a[r] = acc;
        }
        ((float4*)(h + (long)i * 16))[cq] = make_float4(a[0], a[1], a[2], a[3]);
    }
}

__global__ void scatter_kernel(const int* __restrict__ ei32,
                               const long long* __restrict__ ei64,
                               const unsigned int* __restrict__ flag,
                               const float* __restrict__ h,
                               float* __restrict__ summed,
                               float* __restrict__ cnt) {
    long e = (long)blockIdx.x * blockDim.x + threadIdx.x;
    if (e >= N_EDGES) return;
    long src, dst;
    if (*flag) { src = (long)ei64[e]; dst = (long)ei64[N_EDGES + e]; }
    else       { src = (long)ei32[e]; dst = (long)ei32[N_EDGES + e]; }
    const float4* hs = (const float4*)(h + src * 16);
    float4 a = hs[0], b = hs[1], c = hs[2], d = hs[3];
    float* o = summed + dst * 16;
    atomicAdd(o + 0,  a.x); atomicAdd(o + 1,  a.y);
    atomicAdd(o + 2,  a.z); atomicAdd(o + 3,  a.w);
    atomicAdd(o + 4,  b.x); atomicAdd(o + 5,  b.y);
    atomicAdd(o + 6,  b.z); atomicAdd(o + 7,  b.w);
    atomicAdd(o + 8,  c.x); atomicAdd(o + 9,  c.y);
    atomicAdd(o + 10, c.z); atomicAdd(o + 11, c.w);
    atomicAdd(o + 12, d.x); atomicAdd(o + 13, d.y);
    atomicAdd(o + 14, d.z); atomicAdd(o + 15, d.w);
    atomicAdd(cnt + dst, 1.0f);
}

__global__ void finalize_kernel(const float* __restrict__ summed,
                                const float* __restrict__ cnt,
                                const float* __restrict__ b1,
                                const float* __restrict__ W2,
                                const float* __restrict__ b2,
                                float* __restrict__ out, int n) {
    int i = blockIdx.x * blockDim.x + threadIdx.x;
    if (i >= n) return;
    const float4* s = (const float4*)(summed + (long)i * 16);
    float4 s0 = s[0], s1 = s[1], s2 = s[2], s3 = s[3];
    float sv[16] = {s0.x, s0.y, s0.z, s0.w, s1.x, s1.y, s1.z, s1.w,
                    s2.x, s2.y, s2.z, s2.w, s3.x, s3.y, s3.z, s3.w};
    float inv = 1.0f / fmaxf(cnt[i], 1.0f);
    float acc = b2[0];
#pragma unroll
    for (int c = 0; c < 16; ++c)
        acc += W2[c] * fmaxf(sv[c] * inv + b1[c], 0.0f);
    out[i] = acc;
}

extern "C" void kernel_launch(void* const* d_in, const int* in_sizes, int n_in,
                              void* d_out, int out_size, void* d_ws, size_t ws_size,
                              hipStream_t stream) {
    const float* x  = (const float*)d_in[0];
    const void*  ei = d_in[1];
    const float* W1 = (const float*)d_in[2];
    const float* b1 = (const float*)d_in[3];
    const float* W2 = (const float*)d_in[4];
    const float* b2 = (const float*)d_in[5];
    float* out = (float*)d_out;

    float* ws = (float*)d_ws;

    // Bucket-path workspace (4B words):
    //   h2     :   800,000  (fp16 h, __half2[N][8] = 3.2 MB)
    //   packed : 3,200,000  u32 (bucket-grouped edge words)
    //   bcount :   NSCAN    i32 (400,384; block-local prefix after scan1)
    //   bsums  :     1,024  i32 (raw per-bucket totals)
    //   bstart :  NBKT + 1  i32 (bucket bounds; published by scatter blk 0)
    const size_t need_bkt =
        (size_t)(800000 + 3200000 + NSCAN + 1024 + (NBKT + 1)) * 4;

    if (ws_size >= need_bkt) {
        __half2*      h2     = (__half2*)ws;
        unsigned int* packed = (unsigned int*)(ws + 800000);
        int*          bcount = (int*)(ws + 800000 + 3200000);
        int*          bsums  = bcount + NSCAN;
        int*          bstart = bsums + 1024;

        lin_hist_kernel<<<LIN_BLOCKS + EB, 512, 0, stream>>>(
            x, W1, h2, (const int*)ei, (const long long*)ei, bcount);

        scan1_kernel<<<NB_SCAN, SCAN_BLOCK, 0, stream>>>(bcount, bsums, NSCAN);

        scatter_sort_kernel<<<EB, 1024, 0, stream>>>(
            (const int*)ei, (const long long*)ei, bcount, bsums, packed, bstart);

        sort_gather_kernel<<<NBKT, 1024, 0, stream>>>(
            packed, bstart, h2, b1, W2, b2, out);
    } else {
        // Fallback: R0 atomic-scatter path (13.2 MB workspace).
        float* h      = ws;                  // N_NODES * 16
        float* summed = ws + N_NODES * 16;   // N_NODES * 16
        float* cnt    = ws + N_NODES * 32;   // N_NODES
        unsigned int* flag = (unsigned int*)(ws + N_NODES * 33);

        hipMemsetAsync(summed, 0, (size_t)(N_NODES * 17) * sizeof(float), stream);
        detect_i64_kernel<<<1, 64, 0, stream>>>((const unsigned int*)ei, flag);
        linear1_f32_kernel<<<(N_NODES + 127) / 128, 128, 0, stream>>>(x, W1, h, N_NODES);
        scatter_kernel<<<(N_EDGES + 255) / 256, 256, 0, stream>>>(
            (const int*)ei, (const long long*)ei, flag, h, summed, cnt);
        finalize_kernel<<<(N_NODES + 255) / 256, 256, 0, stream>>>(
            summed, cnt, b1, W2, b2, out, N_NODES);
    }
}

// Round 17
// 70.466 us; speedup vs baseline: 1.6913x; 1.0147x over previous
//
#include <hip/hip_runtime.h>
#include <hip/hip_fp16.h>

#define N_NODES 100000
#define N_EDGES 3200000
#define NBKT 782            // buckets of 128 nodes (dst >> 7)
#define EB 512              // phase-A blocks; EB == 2^9 so bsums idx == bucket
#define EPB (N_EDGES / EB)  // 6250 edges per phase-A block
#define SCAN_BLOCK 512
#define NSCAN (NBKT * EB)   // 400384 (bucket-major counts)
#define NB_SCAN ((NSCAN + SCAN_BLOCK - 1) / SCAN_BLOCK)  // 782 == NBKT
#define SORT_CAP 5120       // per-bucket sorted-edge LDS capacity (20 KB)
#define LIN_BLOCKS ((N_NODES + 511) / 512)  // 196 linear-path blocks

// ---------------------------------------------------------------------------
// Wave64-shfl block exclusive scan (int): 3 barriers.
// All NT threads must call; entries beyond the logical n must pass v=0.
// ---------------------------------------------------------------------------
template <int NT>
__device__ __forceinline__ int block_excl_scan(int v, int tid, int* wsum) {
    __syncthreads();                    // protects wsum reuse across calls
    int lane = tid & 63;
    int w = tid >> 6;
    int incl = v;
#pragma unroll
    for (int d = 1; d < 64; d <<= 1) {
        int t = __shfl_up(incl, d, 64);
        if (lane >= d) incl += t;
    }
    if (lane == 63) wsum[w] = incl;
    __syncthreads();
    if (w == 0) {
        constexpr int NW = NT / 64;
        int s = (lane < NW) ? wsum[lane] : 0;
        int si = s;
#pragma unroll
        for (int d = 1; d < NW; d <<= 1) {
            int t = __shfl_up(si, d, 64);
            if (lane >= d) si += t;
        }
        if (lane < NW) wsum[lane] = si - s;   // exclusive wave base
    }
    __syncthreads();
    return incl - v + wsum[w];
}

// ---------------------------------------------------------------------------
// Dual exclusive scan: two independent non-negative int sequences packed in
// one long long (low/high 32). Each half's total < 2^31 so no cross-carry.
// ---------------------------------------------------------------------------
template <int NT>
__device__ __forceinline__ long long block_excl_scan2(long long v, int tid,
                                                      long long* wsum) {
    __syncthreads();
    int lane = tid & 63;
    int w = tid >> 6;
    long long incl = v;
#pragma unroll
    for (int d = 1; d < 64; d <<= 1) {
        long long t = __shfl_up(incl, d, 64);
        if (lane >= d) incl += t;
    }
    if (lane == 63) wsum[w] = incl;
    __syncthreads();
    if (w == 0) {
        constexpr int NW = NT / 64;
        long long s = (lane < NW) ? wsum[lane] : 0;
        long long si = s;
#pragma unroll
        for (int d = 1; d < NW; d <<= 1) {
            long long t = __shfl_up(si, d, 64);
            if (lane >= d) si += t;
        }
        if (lane < NW) wsum[lane] = si - s;
    }
    __syncthreads();
    return incl - v + wsum[w];
}

// ---------------------------------------------------------------------------
// Fused phase A0+A1: blocks [0, LIN_BLOCKS) compute h2 = fp16(x @ W1^T);
// blocks [LIN_BLOCKS, LIN_BLOCKS+EB) histogram dst buckets (LDS atomics,
// deterministic bucket-major bcount writes). Both paths block-uniform.
// ---------------------------------------------------------------------------
__global__ void lin_hist_kernel(const float* __restrict__ x,
                                const float* __restrict__ W1,
                                __half2* __restrict__ h2,
                                const int* __restrict__ ei32,
                                const long long* __restrict__ ei64,
                                int* __restrict__ bcount) {
    __shared__ float w[16 * 58];
    __shared__ int hist[NBKT];
    __shared__ int dflag;
    int tid = threadIdx.x;

    if (blockIdx.x < LIN_BLOCKS) {
        // ---- linear1 path ----
        for (int idx = tid; idx < 16 * 58; idx += 512) w[idx] = W1[idx];
        __syncthreads();

        int i = blockIdx.x * 512 + tid;
        if (i >= N_NODES) return;

        float xv[58];
        const float* xr = x + (long)i * 58;
#pragma unroll
        for (int k = 0; k < 58; ++k) xv[k] = xr[k];

        __half2 o[8];
#pragma unroll
        for (int q = 0; q < 8; ++q) {
            float a[2];
#pragma unroll
            for (int r = 0; r < 2; ++r) {
                int c = q * 2 + r;
                float acc = 0.0f;
#pragma unroll
                for (int k = 0; k < 58; ++k) acc += xv[k] * w[c * 58 + k];
                a[r] = acc;
            }
            o[q] = __floats2half2_rn(a[0], a[1]);
        }
        float4* dst = (float4*)(h2 + (long)i * 8);
        float4* src = (float4*)o;
        dst[0] = src[0];
        dst[1] = src[1];
    } else {
        // ---- hist path ----
        int blk = blockIdx.x - LIN_BLOCKS;
        if (tid == 0) dflag = 0;
        for (int i = tid; i < NBKT; i += 512) hist[i] = 0;
        __syncthreads();
        if (((const unsigned int*)ei32)[2 * tid + 1] != 0u) atomicOr(&dflag, 1);
        __syncthreads();
        bool i64 = (dflag == 0);

        long base = (long)blk * EPB;
        for (int k = tid; k < EPB; k += 512) {
            long e = base + k;
            int dst = i64 ? (int)ei64[N_EDGES + e] : ei32[N_EDGES + e];
            atomicAdd(&hist[dst >> 7], 1);
        }
        __syncthreads();
        for (int b = tid; b < NBKT; b += 512)
            bcount[(long)b * EB + blk] = hist[b];
    }
}

// ---------------------------------------------------------------------------
// scan1: block-local exclusive scan of bcount in place + raw block totals.
// Block b handles bucket b's 512 per-block counts; bsums[b] = bucket total.
// ---------------------------------------------------------------------------
__global__ void __launch_bounds__(SCAN_BLOCK)
scan1_kernel(int* __restrict__ data, int* __restrict__ bsums, int n) {
    __shared__ int wsum[16];
    int i = blockIdx.x * SCAN_BLOCK + threadIdx.x;
    int v = (i < n) ? data[i] : 0;
    int excl = block_excl_scan<SCAN_BLOCK>(v, threadIdx.x, wsum);
    if (i < n) data[i] = excl;
    if (threadIdx.x == SCAN_BLOCK - 1) bsums[blockIdx.x] = excl + v;
}

// ---------------------------------------------------------------------------
// Phase A2: LDS-sorted scatter. Pass 1 reads dst once (cached in LDS) +
// histogram; ONE dual shfl-scan gives both the local offsets and the
// cross-bucket base (bsums scan); block 0 publishes bstart[] for phase B.
// Pass 2 reads only src; pass 3 streams bucket-grouped dense chunks out.
// ---------------------------------------------------------------------------
__global__ void __launch_bounds__(1024, 8)
scatter_sort_kernel(const int* __restrict__ ei32,
                    const long long* __restrict__ ei64,
                    const int* __restrict__ bcount,
                    const int* __restrict__ bsums,
                    unsigned int* __restrict__ packed,
                    int* __restrict__ bstart) {
    __shared__ unsigned int vals[EPB];        // 25.0 KB bucket-grouped words
    __shared__ unsigned int dstin[EPB];       // 25.0 KB cached dst per slot
    __shared__ unsigned short bjs[EPB];       // 12.5 KB bucket id per slot
    __shared__ int hist[NBKT];
    __shared__ int curs[NBKT];
    __shared__ int gbase[NBKT];
    __shared__ long long wsumll[16];
    __shared__ int dflag;

    int tid = threadIdx.x;
    if (tid == 0) dflag = 0;
    for (int i = tid; i < NBKT; i += 1024) hist[i] = 0;
    __syncthreads();
    if (tid < 512 && ((const unsigned int*)ei32)[2 * tid + 1] != 0u)
        atomicOr(&dflag, 1);
    __syncthreads();
    bool i64 = (dflag == 0);
    long base = (long)blockIdx.x * EPB;

    // pass 1: read dst once -> LDS cache + per-bucket histogram
    for (int k = tid; k < EPB; k += 1024) {
        long e = base + k;
        int dst = i64 ? (int)ei64[N_EDGES + e] : ei32[N_EDGES + e];
        dstin[k] = (unsigned int)dst;
        atomicAdd(&hist[dst >> 7], 1);
    }
    __syncthreads();

    // dual scan: low = local hist (sum <= 6250), high = bsums (sum <= 3.2M)
    int hv = (tid < NBKT) ? hist[tid] : 0;
    int bv = (tid < NBKT) ? bsums[tid] : 0;
    long long pk = ((long long)bv << 32) | (unsigned int)hv;
    long long sc = block_excl_scan2<1024>(pk, tid, wsumll);
    int lexcl = (int)(sc & 0xFFFFFFFFll);
    int sb = (int)(sc >> 32);
    if (tid < NBKT) {
        // gi = tid*EB + blockIdx.x; gi>>9 == tid since EB == 512
        long gi = (long)tid * EB + blockIdx.x;
        curs[tid] = lexcl;
        gbase[tid] = bcount[gi] + sb - lexcl;
    }
    if (blockIdx.x == 0) {
        if (tid < NBKT) bstart[tid] = sb;
        if (tid == 0) bstart[NBKT] = N_EDGES;
    }
    __syncthreads();

    // pass 2: src from global (first touch), dst from LDS; cursor-scatter
    for (int k = tid; k < EPB; k += 1024) {
        long e = base + k;
        int src = i64 ? (int)ei64[e] : ei32[e];
        unsigned int dst = dstin[k];
        int b = (int)(dst >> 7);
        int p = atomicAdd(&curs[b], 1);
        vals[p] = ((dst & 127u) << 17) | (unsigned int)src;
        bjs[p] = (unsigned short)b;
    }
    __threadfence_block();
    __syncthreads();

    // pass 3: dense-chunk copy to global
    for (int j = tid; j < EPB; j += 1024)
        packed[gbase[bjs[j]] + j] = vals[j];
}

// ---------------------------------------------------------------------------
// Phase B (fused): per-bucket counting sort in LDS + register gather.
// 512 threads, ~22 KB LDS -> 4 blocks/CU, 2048 threads/CU: all 782 blocks
// co-resident in ONE wave (was 782 over a 512-block wave = 76% util).
// packed is read from global in both passes (2nd pass is L2-hot).
// Gather: two node-passes of 64 nodes x 8 lanes.
// ---------------------------------------------------------------------------
__global__ void __launch_bounds__(512, 8)
sort_gather_kernel(const unsigned int* __restrict__ packed,
                   const int* __restrict__ bstart,
                   const __half2* __restrict__ h2,
                   const float* __restrict__ b1,
                   const float* __restrict__ W2,
                   const float* __restrict__ b2,
                   float* __restrict__ out) {
    __shared__ unsigned int sortedv[SORT_CAP]; // 20 KB node-grouped srcs
    __shared__ int hist[128];
    __shared__ int starts[128];
    __shared__ int curs[128];
    __shared__ int wsum[8];

    int b = blockIdx.x;
    int tid = threadIdx.x;
    int start = bstart[b];
    int end = bstart[b + 1];
    int m = end - start;
    bool fast = (m <= SORT_CAP);   // uniform across the block

    if (tid < 128) hist[tid] = 0;
    __syncthreads();

    // 1. per-node histogram (global read; lines stay L2/L1-hot for pass 3)
    for (int k = tid; k < m; k += 512)
        atomicAdd(&hist[(int)(packed[start + k] >> 17)], 1);
    __syncthreads();

    // 2. exclusive scan of the 128 node counts (shfl-based)
    int hv = (tid < 128) ? hist[tid] : 0;
    int nexcl = block_excl_scan<512>(hv, tid, wsum);
    if (tid < 128) {
        starts[tid] = nexcl;
        curs[tid] = nexcl;
    }
    __syncthreads();

    if (fast) {
        // 3. cursor-scatter src into sortedv[] (global re-read, L2-hot)
        for (int k = tid; k < m; k += 512) {
            unsigned int w = packed[start + k];
            int l = (int)(w >> 17);
            int p = atomicAdd(&curs[l], 1);
            sortedv[p] = w & 0x1FFFFu;
        }
        __threadfence_block();
    }
    __syncthreads();

    // 4. register gather from LDS: 2 passes x (64 nodes x 8 lanes), unroll-8
    int c = tid & 7;               // channel pair 0..7
#pragma unroll
    for (int pass = 0; pass < 2; ++pass) {
        int l = pass * 64 + (tid >> 3);   // node-in-bucket 0..127
        int g = b * 128 + l;
        if (g >= N_NODES) continue;       // no barriers below

        int deg = hist[l];
        float2 acc0 = {0.0f, 0.0f}, acc1 = {0.0f, 0.0f};
        float2 acc2 = {0.0f, 0.0f}, acc3 = {0.0f, 0.0f};

        if (fast) {
            int p = starts[l], pend = p + deg;
            for (; p + 7 < pend; p += 8) {
                int s0 = (int)sortedv[p];
                int s1 = (int)sortedv[p + 1];
                int s2 = (int)sortedv[p + 2];
                int s3 = (int)sortedv[p + 3];
                int s4 = (int)sortedv[p + 4];
                int s5 = (int)sortedv[p + 5];
                int s6 = (int)sortedv[p + 6];
                int s7 = (int)sortedv[p + 7];
                float2 f0 = __half22float2(h2[(long)s0 * 8 + c]);
                float2 f1 = __half22float2(h2[(long)s1 * 8 + c]);
                float2 f2 = __half22float2(h2[(long)s2 * 8 + c]);
                float2 f3 = __half22float2(h2[(long)s3 * 8 + c]);
                float2 f4 = __half22float2(h2[(long)s4 * 8 + c]);
                float2 f5 = __half22float2(h2[(long)s5 * 8 + c]);
                float2 f6 = __half22float2(h2[(long)s6 * 8 + c]);
                float2 f7 = __half22float2(h2[(long)s7 * 8 + c]);
                acc0.x += f0.x + f4.x; acc0.y += f0.y + f4.y;
                acc1.x += f1.x + f5.x; acc1.y += f1.y + f5.y;
                acc2.x += f2.x + f6.x; acc2.y += f2.y + f6.y;
                acc3.x += f3.x + f7.x; acc3.y += f3.y + f7.y;
            }
            for (; p + 1 < pend; p += 2) {
                int sA = (int)sortedv[p];
                int sB = (int)sortedv[p + 1];
                float2 fA = __half22float2(h2[(long)sA * 8 + c]);
                float2 fB = __half22float2(h2[(long)sB * 8 + c]);
                acc0.x += fA.x; acc0.y += fA.y;
                acc1.x += fB.x; acc1.y += fB.y;
            }
            if (p < pend) {
                float2 f = __half22float2(h2[(long)sortedv[p] * 8 + c]);
                acc0.x += f.x; acc0.y += f.y;
            }
        } else {
            // never-expected universal fallback: filter-scan global packed
            for (int p = start; p < end; ++p) {
                unsigned int w = packed[p];
                if ((int)(w >> 17) == l) {
                    float2 f = __half22float2(h2[(long)(w & 0x1FFFFu) * 8 + c]);
                    acc0.x += f.x; acc0.y += f.y;
                }
            }
        }

        float inv = 1.0f / fmaxf((float)deg, 1.0f);
        float sx = acc0.x + acc1.x + acc2.x + acc3.x;
        float sy = acc0.y + acc1.y + acc2.y + acc3.y;
        float vv = fmaxf(sx * inv + b1[2 * c], 0.0f)     * W2[2 * c]
                 + fmaxf(sy * inv + b1[2 * c + 1], 0.0f) * W2[2 * c + 1];
        vv += __shfl_xor(vv, 1);
        vv += __shfl_xor(vv, 2);
        vv += __shfl_xor(vv, 4);
        if (c == 0) out[g] = vv + b2[0];
    }
}

// ---------------------------------------------------------------------------
// Fallback path (R0): atomic value scatter + finalize. Used if ws too small.
// ---------------------------------------------------------------------------
__global__ void detect_i64_kernel(const unsigned int* __restrict__ ei,
                                  unsigned int* __restrict__ flag) {
    unsigned int v = 0;
    int lane = threadIdx.x;  // 64 threads
    for (int j = lane; j < 512; j += 64) v |= ei[2 * j + 1];
    unsigned long long any_nonzero = __ballot(v != 0u);
    if (lane == 0) *flag = (any_nonzero == 0ULL) ? 1u : 0u;
}

__global__ void linear1_f32_kernel(const float* __restrict__ x,
                                   const float* __restrict__ W1,
                                   float* __restrict__ h, int n) {
    __shared__ float w[16 * 58];
    for (int idx = threadIdx.x; idx < 16 * 58; idx += blockDim.x)
        w[idx] = W1[idx];
    __syncthreads();
    int i = blockIdx.x * blockDim.x + threadIdx.x;
    if (i >= n) return;
    float xv[58];
    const float* xr = x + (long)i * 58;
#pragma unroll
    for (int k = 0; k < 58; ++k) xv[k] = xr[k];
#pragma unroll
    for (int cq = 0; cq < 4; ++cq) {
        float a[4];
#pragma unroll
        for (int r = 0; r < 4; ++r) {
            int ch = cq * 4 + r;
            float acc = 0.0f;
#pragma unroll
            for (int k = 0; k < 58; ++k) acc += xv[k] * w[ch * 58 + k];
            a[r] = acc;
        }
        ((float4*)(h + (long)i * 16))[cq] = make_float4(a[0], a[1], a[2], a[3]);
    }
}

__global__ void scatter_kernel(const int* __restrict__ ei32,
                               const long long* __restrict__ ei64,
                               const unsigned int* __restrict__ flag,
                               const float* __restrict__ h,
                               float* __restrict__ summed,
                               float* __restrict__ cnt) {
    long e = (long)blockIdx.x * blockDim.x + threadIdx.x;
    if (e >= N_EDGES) return;
    long src, dst;
    if (*flag) { src = (long)ei64[e]; dst = (long)ei64[N_EDGES + e]; }
    else       { src = (long)ei32[e]; dst = (long)ei32[N_EDGES + e]; }
    const float4* hs = (const float4*)(h + src * 16);
    float4 a = hs[0], b = hs[1], c = hs[2], d = hs[3];
    float* o = summed + dst * 16;
    atomicAdd(o + 0,  a.x); atomicAdd(o + 1,  a.y);
    atomicAdd(o + 2,  a.z); atomicAdd(o + 3,  a.w);
    atomicAdd(o + 4,  b.x); atomicAdd(o + 5,  b.y);
    atomicAdd(o + 6,  b.z); atomicAdd(o + 7,  b.w);
    atomicAdd(o + 8,  c.x); atomicAdd(o + 9,  c.y);
    atomicAdd(o + 10, c.z); atomicAdd(o + 11, c.w);
    atomicAdd(o + 12, d.x); atomicAdd(o + 13, d.y);
    atomicAdd(o + 14, d.z); atomicAdd(o + 15, d.w);
    atomicAdd(cnt + dst, 1.0f);
}

__global__ void finalize_kernel(const float* __restrict__ summed,
                                const float* __restrict__ cnt,
                                const float* __restrict__ b1,
                                const float* __restrict__ W2,
                                const float* __restrict__ b2,
                                float* __restrict__ out, int n) {
    int i = blockIdx.x * blockDim.x + threadIdx.x;
    if (i >= n) return;
    const float4* s = (const float4*)(summed + (long)i * 16);
    float4 s0 = s[0], s1 = s[1], s2 = s[2], s3 = s[3];
    float sv[16] = {s0.x, s0.y, s0.z, s0.w, s1.x, s1.y, s1.z, s1.w,
                    s2.x, s2.y, s2.z, s2.w, s3.x, s3.y, s3.z, s3.w};
    float inv = 1.0f / fmaxf(cnt[i], 1.0f);
    float acc = b2[0];
#pragma unroll
    for (int c = 0; c < 16; ++c)
        acc += W2[c] * fmaxf(sv[c] * inv + b1[c], 0.0f);
    out[i] = acc;
}

extern "C" void kernel_launch(void* const* d_in, const int* in_sizes, int n_in,
                              void* d_out, int out_size, void* d_ws, size_t ws_size,
                              hipStream_t stream) {
    const float* x  = (const float*)d_in[0];
    const void*  ei = d_in[1];
    const float* W1 = (const float*)d_in[2];
    const float* b1 = (const float*)d_in[3];
    const float* W2 = (const float*)d_in[4];
    const float* b2 = (const float*)d_in[5];
    float* out = (float*)d_out;

    float* ws = (float*)d_ws;

    // Bucket-path workspace (4B words):
    //   h2     :   800,000  (fp16 h, __half2[N][8] = 3.2 MB)
    //   packed : 3,200,000  u32 (bucket-grouped edge words)
    //   bcount :   NSCAN    i32 (400,384; block-local prefix after scan1)
    //   bsums  :     1,024  i32 (raw per-bucket totals)
    //   bstart :  NBKT + 1  i32 (bucket bounds; published by scatter blk 0)
    const size_t need_bkt =
        (size_t)(800000 + 3200000 + NSCAN + 1024 + (NBKT + 1)) * 4;

    if (ws_size >= need_bkt) {
        __half2*      h2     = (__half2*)ws;
        unsigned int* packed = (unsigned int*)(ws + 800000);
        int*          bcount = (int*)(ws + 800000 + 3200000);
        int*          bsums  = bcount + NSCAN;
        int*          bstart = bsums + 1024;

        lin_hist_kernel<<<LIN_BLOCKS + EB, 512, 0, stream>>>(
            x, W1, h2, (const int*)ei, (const long long*)ei, bcount);

        scan1_kernel<<<NB_SCAN, SCAN_BLOCK, 0, stream>>>(bcount, bsums, NSCAN);

        scatter_sort_kernel<<<EB, 1024, 0, stream>>>(
            (const int*)ei, (const long long*)ei, bcount, bsums, packed, bstart);

        sort_gather_kernel<<<NBKT, 512, 0, stream>>>(
            packed, bstart, h2, b1, W2, b2, out);
    } else {
        // Fallback: R0 atomic-scatter path (13.2 MB workspace).
        float* h      = ws;                  // N_NODES * 16
        float* summed = ws + N_NODES * 16;   // N_NODES * 16
        float* cnt    = ws + N_NODES * 32;   // N_NODES
        unsigned int* flag = (unsigned int*)(ws + N_NODES * 33);

        hipMemsetAsync(summed, 0, (size_t)(N_NODES * 17) * sizeof(float), stream);
        detect_i64_kernel<<<1, 64, 0, stream>>>((const unsigned int*)ei, flag);
        linear1_f32_kernel<<<(N_NODES + 127) / 128, 128, 0, stream>>>(x, W1, h, N_NODES);
        scatter_kernel<<<(N_EDGES + 255) / 256, 256, 0, stream>>>(
            (const int*)ei, (const long long*)ei, flag, h, summed, cnt);
        finalize_kernel<<<(N_NODES + 255) / 256, 256, 0, stream>>>(
            summed, cnt, b1, W2, b2, out, N_NODES);
    }
}